// Round 5
// baseline (635.679 us; speedup 1.0000x reference)
//
#include <hip/hip_runtime.h>
#include <math.h>

#define N_NODES 100000
#define N_EDGES 1600000
#define F_IN    4
#define HID     128
#define N_CLS   5
#define N_GRAPH 256
#define POOL_SEG 8

typedef _Float16 f16;
typedef _Float16 f16x2 __attribute__((ext_vector_type(2)));
typedef _Float16 f16x4 __attribute__((ext_vector_type(4)));
typedef _Float16 f16x8 __attribute__((ext_vector_type(8)));
typedef float f32x4 __attribute__((ext_vector_type(4)));

// decode 4-byte edge record: [src:17 | coef-f16-positive:15]
__device__ __forceinline__ float rec_coef(unsigned r) {
    return (float)__builtin_bit_cast(_Float16, (unsigned short)(r & 0x7FFFu));
}

// ---------------- degree histogram over dst; atomic old value = edge rank within row --------
__global__ __launch_bounds__(256) void k_hist(const int* __restrict__ dst, int* __restrict__ deg,
                                              int* __restrict__ rank) {
    int e = blockIdx.x * 256 + threadIdx.x;
    if (e < N_EDGES) rank[e] = atomicAdd(&deg[dst[e]], 1);
}

// ---------------- exclusive scan (3-pass) ---------------
__global__ __launch_bounds__(256) void k_scan1(const int* __restrict__ cnt, int* __restrict__ excl,
                                               int* __restrict__ bsum) {
    __shared__ int s[256];
    int i = blockIdx.x * 256 + threadIdx.x;
    int v = (i < N_NODES) ? cnt[i] : 0;
    s[threadIdx.x] = v;
    __syncthreads();
    for (int off = 1; off < 256; off <<= 1) {
        int t = (threadIdx.x >= off) ? s[threadIdx.x - off] : 0;
        __syncthreads();
        s[threadIdx.x] += t;
        __syncthreads();
    }
    if (i < N_NODES) excl[i] = s[threadIdx.x] - v;
    if (threadIdx.x == 255) bsum[blockIdx.x] = s[255];
}

__global__ __launch_bounds__(512) void k_scan2(int* __restrict__ bsum, int nb) {
    __shared__ int s[512];
    int v = (threadIdx.x < nb) ? bsum[threadIdx.x] : 0;
    s[threadIdx.x] = v;
    __syncthreads();
    for (int off = 1; off < 512; off <<= 1) {
        int t = (threadIdx.x >= off) ? s[threadIdx.x - off] : 0;
        __syncthreads();
        s[threadIdx.x] += t;
        __syncthreads();
    }
    if (threadIdx.x < nb) bsum[threadIdx.x] = s[threadIdx.x] - v;
}

// scan3 + dinv fused
__global__ __launch_bounds__(256) void k_scan3(int* __restrict__ excl, const int* __restrict__ bsum,
                                               const int* __restrict__ deg, float* __restrict__ dinv) {
    int i = blockIdx.x * 256 + threadIdx.x;
    if (i < N_NODES) {
        excl[i] += bsum[blockIdx.x];
        dinv[i] = rsqrtf((float)deg[i] + 1.0f);
    }
    if (i == 0) excl[N_NODES] = N_EDGES;
}

// ---------------- CSR fill: no atomics; one 4B scattered write per edge ---------------
__global__ __launch_bounds__(256) void k_fill(const int* __restrict__ src, const int* __restrict__ dst,
                                              const int* __restrict__ rank,
                                              const int* __restrict__ rowptr,
                                              const float* __restrict__ dinv,
                                              unsigned* __restrict__ edges) {
    int e = blockIdx.x * 256 + threadIdx.x;
    if (e < N_EDGES) {
        int d = dst[e], s = src[e];
        int ppos = rowptr[d] + rank[e];
        float c = dinv[s] * dinv[d];
        unsigned short cb = __builtin_bit_cast(unsigned short, (f16)c);
        edges[ppos] = ((unsigned)s << 15) | (unsigned)(cb & 0x7FFFu);
    }
}

// ---------------- aggregate raw features x (N x 4) — Agg(x) before the layer-1 GEMM ----------
__global__ __launch_bounds__(256) void k_aggx(const float4* __restrict__ x, const int* __restrict__ rowptr,
                                              const unsigned* __restrict__ edges,
                                              const float* __restrict__ dinv, float4* __restrict__ out) {
    int i = blockIdx.x * 256 + threadIdx.x;
    if (i >= N_NODES) return;
    float di = dinv[i];
    float4 xv = x[i];
    float c0 = di * di;
    float ax = c0 * xv.x, ay = c0 * xv.y, az = c0 * xv.z, aw = c0 * xv.w;
    int beg = rowptr[i], end = rowptr[i + 1];
    for (int e = beg; e < end; ++e) {
        unsigned r = edges[e];
        float c = rec_coef(r);
        float4 v = x[r >> 15];
        ax = fmaf(c, v.x, ax); ay = fmaf(c, v.y, ay);
        az = fmaf(c, v.z, az); aw = fmaf(c, v.w, aw);
    }
    out[i] = make_float4(ax, ay, az, aw);
}

// ---------------- layer-1 GEMM: (N x 4) @ (4 x 128) + bias, ReLU, fp16 out ---------------
__global__ __launch_bounds__(256) void k_gemm4(const float4* __restrict__ A, const float* __restrict__ W,
                                               const float* __restrict__ bias, f16x2* __restrict__ out) {
    int idx = blockIdx.x * 256 + threadIdx.x;      // idx = i*64 + fpair
    int i = idx >> 6, fp = (idx & 63) * 2;
    float4 a = A[i];
    float v0 = bias[fp];
    v0 = fmaf(a.x, W[fp],           v0);
    v0 = fmaf(a.y, W[HID + fp],     v0);
    v0 = fmaf(a.z, W[2 * HID + fp], v0);
    v0 = fmaf(a.w, W[3 * HID + fp], v0);
    float v1 = bias[fp + 1];
    v1 = fmaf(a.x, W[fp + 1],           v1);
    v1 = fmaf(a.y, W[HID + fp + 1],     v1);
    v1 = fmaf(a.z, W[2 * HID + fp + 1], v1);
    v1 = fmaf(a.w, W[3 * HID + fp + 1], v1);
    f16x2 o;
    o.x = (f16)fmaxf(v0, 0.0f);
    o.y = (f16)fmaxf(v1, 0.0f);
    out[idx] = o;
}

// ---------------- pack 3x W (128x128 fp32) into MFMA B-fragment order, fp16, one launch -----
// Wp[w][((ct*4 + ks)*64 + lane)*8 + j] = W[ks*32 + (lane>>4)*8 + j][ct*16 + (lane&15)]
__global__ __launch_bounds__(256) void k_packW3(const float* __restrict__ W2, const float* __restrict__ W3,
                                                const float* __restrict__ W4, f16* __restrict__ Wp) {
    int idx = blockIdx.x * 256 + threadIdx.x;   // 192 blocks x 256 = 49152 = 3 * 16384
    int which = idx >> 14;
    int r = idx & 16383;
    const float* W = (which == 0) ? W2 : (which == 1) ? W3 : W4;
    int j  = r & 7;
    int L  = (r >> 3) & 63;
    int ks = (r >> 9) & 3;
    int ct = r >> 11;
    int k = ks * 32 + (L >> 4) * 8 + j;
    int n = ct * 16 + (L & 15);
    Wp[idx] = (f16)W[k * HID + n];
}

// ---------------- FUSED layer: Agg (CSR gather) -> LDS strip -> MFMA GEMM + bias + ReLU ------
// One wave owns 16 nodes: aggregates them into a swizzled 4KB LDS strip, then computes the
// 16x128 output strip with mfma_f32_16x16x32_f16. No inter-wave dependency, no barrier.
// LDS layout (per strip, f16x2 words): word(m, w) = m*64 + (w ^ ((m&7)<<2))  [2-way = free]
__global__ __launch_bounds__(256) void k_aggemm(const f16x2* __restrict__ h,
                                                const int* __restrict__ rowptr,
                                                const unsigned* __restrict__ edges,
                                                const float* __restrict__ dinv,
                                                const f16* __restrict__ Wp,
                                                const float* __restrict__ bias,
                                                f16* __restrict__ out) {
    __shared__ f16x2 sh[4][16 * 64];   // 16 KB: 4 waves x (16 nodes x 128 f16)
    int wave = threadIdx.x >> 6;
    int lane = threadIdx.x & 63;
    int node0 = blockIdx.x * 64 + wave * 16;
    if (node0 >= N_NODES) return;     // N_NODES % 16 == 0, so active waves have 16 full nodes
    f16x2* S = sh[wave];

    // ---- phase 1: aggregate 16 nodes (whole wave per node, f16x2 per lane) ----
    for (int i = 0; i < 16; ++i) {
        int node = node0 + i;
        int beg = rowptr[node], end = rowptr[node + 1];
        float di = dinv[node];
        f16x2 self = h[node * 64 + lane];
        float c0 = di * di;
        float accx = c0 * (float)self.x;
        float accy = c0 * (float)self.y;
        int e = beg;
        for (; e + 8 <= end; e += 8) {
            unsigned r0 = edges[e + 0], r1 = edges[e + 1], r2 = edges[e + 2], r3 = edges[e + 3];
            unsigned r4 = edges[e + 4], r5 = edges[e + 5], r6 = edges[e + 6], r7 = edges[e + 7];
            f16x2 v0 = h[(r0 >> 15) * 64 + lane], v1 = h[(r1 >> 15) * 64 + lane];
            f16x2 v2 = h[(r2 >> 15) * 64 + lane], v3 = h[(r3 >> 15) * 64 + lane];
            f16x2 v4 = h[(r4 >> 15) * 64 + lane], v5 = h[(r5 >> 15) * 64 + lane];
            f16x2 v6 = h[(r6 >> 15) * 64 + lane], v7 = h[(r7 >> 15) * 64 + lane];
            float c0f = rec_coef(r0), c1f = rec_coef(r1), c2f = rec_coef(r2), c3f = rec_coef(r3);
            float c4f = rec_coef(r4), c5f = rec_coef(r5), c6f = rec_coef(r6), c7f = rec_coef(r7);
            accx = fmaf(c0f, (float)v0.x, accx); accy = fmaf(c0f, (float)v0.y, accy);
            accx = fmaf(c1f, (float)v1.x, accx); accy = fmaf(c1f, (float)v1.y, accy);
            accx = fmaf(c2f, (float)v2.x, accx); accy = fmaf(c2f, (float)v2.y, accy);
            accx = fmaf(c3f, (float)v3.x, accx); accy = fmaf(c3f, (float)v3.y, accy);
            accx = fmaf(c4f, (float)v4.x, accx); accy = fmaf(c4f, (float)v4.y, accy);
            accx = fmaf(c5f, (float)v5.x, accx); accy = fmaf(c5f, (float)v5.y, accy);
            accx = fmaf(c6f, (float)v6.x, accx); accy = fmaf(c6f, (float)v6.y, accy);
            accx = fmaf(c7f, (float)v7.x, accx); accy = fmaf(c7f, (float)v7.y, accy);
        }
        for (; e < end; ++e) {
            unsigned r = edges[e];
            f16x2 v = h[(r >> 15) * 64 + lane];
            float c = rec_coef(r);
            accx = fmaf(c, (float)v.x, accx);
            accy = fmaf(c, (float)v.y, accy);
        }
        f16x2 o;
        o.x = (f16)accx;
        o.y = (f16)accy;
        S[i * 64 + (lane ^ ((i & 7) << 2))] = o;    // swizzled store, 2-way (free)
    }

    // ---- phase 2: 16x128 MFMA strip from LDS A-frags + global Wp B-frags ----
    int m = lane & 15;
    int q = lane >> 4;
    f32x4 acc[8];
#pragma unroll
    for (int t = 0; t < 8; ++t) acc[t] = (f32x4){0.f, 0.f, 0.f, 0.f};

#pragma unroll
    for (int ks = 0; ks < 4; ++ks) {
        // A[m][ks*32 + q*8 + j], j=0..7 -> f16x2 words w = ks*16 + q*4 .. +3 (swizzled)
        int w = m * 64 + (((ks * 16 + q * 4)) ^ ((m & 7) << 2));
        f16x8 a = *(const f16x8*)&S[w];
#pragma unroll
        for (int t = 0; t < 8; ++t) {
            f16x8 b = *(const f16x8*)(Wp + ((size_t)(t * 4 + ks) * 64 + lane) * 8);
            acc[t] = __builtin_amdgcn_mfma_f32_16x16x32_f16(a, b, acc[t], 0, 0, 0);
        }
    }

    int orow = node0 + q * 4;
#pragma unroll
    for (int t = 0; t < 8; ++t) {
        float bb = bias[t * 16 + m];
#pragma unroll
        for (int r = 0; r < 4; ++r) {
            out[(size_t)(orow + r) * HID + t * 16 + m] = (f16)fmaxf(acc[t][r] + bb, 0.0f);
        }
    }
}

// ---------------- pooling pass 1: per (graph, segment) partial sums, fp32, deterministic -----
__device__ __forceinline__ int lower_bound_batch(const int* __restrict__ batch, int val) {
    int lo = 0, hi = N_NODES;
    while (lo < hi) { int m = (lo + hi) >> 1; if (batch[m] < val) lo = m + 1; else hi = m; }
    return lo;
}

__global__ __launch_bounds__(128) void k_pool1(const f16* __restrict__ h, const int* __restrict__ batch,
                                               float* __restrict__ partials) {
    int g = blockIdx.x / POOL_SEG;
    int s = blockIdx.x % POOL_SEG;
    int f = threadIdx.x;
    int beg = lower_bound_batch(batch, g);
    int end = lower_bound_batch(batch, g + 1);
    int len = end - beg;
    int sb = beg + (int)(((long long)len * s) / POOL_SEG);
    int se = beg + (int)(((long long)len * (s + 1)) / POOL_SEG);
    float acc = 0.0f;
    for (int i = sb; i < se; ++i) acc += (float)h[i * HID + f];
    partials[(size_t)blockIdx.x * HID + f] = acc;
}

// ---------------- pooling pass 2 + head fused ---------------
__global__ __launch_bounds__(128) void k_pool2h(const float* __restrict__ partials,
                                                const int* __restrict__ batch,
                                                const float* __restrict__ Wl, const float* __restrict__ bl,
                                                float* __restrict__ out) {
    __shared__ float sp[HID];
    int g = blockIdx.x;
    int f = threadIdx.x;
    float acc = 0.0f;
#pragma unroll
    for (int s = 0; s < POOL_SEG; ++s)
        acc += partials[(size_t)(g * POOL_SEG + s) * HID + f];
    int beg = lower_bound_batch(batch, g);
    int end = lower_bound_batch(batch, g + 1);
    sp[f] = acc / fmaxf((float)(end - beg), 1.0f);
    __syncthreads();
    if (f < N_CLS) {
        float v = bl[f];
        for (int k = 0; k < HID; ++k) v = fmaf(sp[k], Wl[k * N_CLS + f], v);
        out[g * N_CLS + f] = 1.0f / (1.0f + expf(-v));
    }
}

extern "C" void kernel_launch(void* const* d_in, const int* in_sizes, int n_in,
                              void* d_out, int out_size, void* d_ws, size_t ws_size,
                              hipStream_t stream) {
    const float* x     = (const float*)d_in[0];
    const int*   ei    = (const int*)d_in[1];
    const int*   batch = (const int*)d_in[2];
    const float* W1 = (const float*)d_in[3];  const float* b1 = (const float*)d_in[4];
    const float* W2 = (const float*)d_in[5];  const float* b2 = (const float*)d_in[6];
    const float* W3 = (const float*)d_in[7];  const float* b3 = (const float*)d_in[8];
    const float* W4 = (const float*)d_in[9];  const float* b4 = (const float*)d_in[10];
    const float* Wl = (const float*)d_in[11]; const float* bl = (const float*)d_in[12];
    float* out = (float*)d_out;

    char* p = (char*)d_ws;
    auto alloc = [&](size_t bytes) { char* r = p; p += (bytes + 255) & ~(size_t)255; return (void*)r; };
    int*      deg    = (int*)     alloc((size_t)N_NODES * 4);
    int*      rowptr = (int*)     alloc((size_t)(N_NODES + 1) * 4);
    int*      rank   = (int*)     alloc((size_t)N_EDGES * 4);
    int*      bsum   = (int*)     alloc(512 * 4);
    float*    dinv   = (float*)   alloc((size_t)N_NODES * 4);
    unsigned* edges  = (unsigned*)alloc((size_t)N_EDGES * 4);
    float*    xagg   = (float*)   alloc((size_t)N_NODES * F_IN * 4);
    f16*      h0     = (f16*)     alloc((size_t)N_NODES * HID * 2);
    f16*      h1     = (f16*)     alloc((size_t)N_NODES * HID * 2);
    float*    parts  = (float*)   alloc((size_t)N_GRAPH * POOL_SEG * HID * 4);
    f16*      Wp     = (f16*)     alloc((size_t)3 * HID * HID * 2);
    f16*      Wp2 = Wp;
    f16*      Wp3 = Wp + HID * HID;
    f16*      Wp4 = Wp + 2 * HID * HID;

    const int* srcv = ei;              // edge_index[0]
    const int* dstv = ei + N_EDGES;    // edge_index[1]

    hipMemsetAsync(deg, 0, (size_t)N_NODES * 4, stream);

    const int nb = (N_NODES + 255) / 256;   // 391

    k_hist  <<<N_EDGES / 256, 256, 0, stream>>>(dstv, deg, rank);
    k_scan1 <<<nb, 256, 0, stream>>>(deg, rowptr, bsum);
    k_scan2 <<<1, 512, 0, stream>>>(bsum, nb);
    k_scan3 <<<nb, 256, 0, stream>>>(rowptr, bsum, deg, dinv);
    k_fill  <<<N_EDGES / 256, 256, 0, stream>>>(srcv, dstv, rank, rowptr, dinv, edges);
    k_packW3<<<192, 256, 0, stream>>>(W2, W3, W4, Wp);

    // layer 1: Agg(x) @ W1  (aggregate the 4-wide features, then expand to 128)
    k_aggx <<<nb, 256, 0, stream>>>((const float4*)x, rowptr, edges, dinv, (float4*)xagg);
    k_gemm4<<<(N_NODES * 64) / 256, 256, 0, stream>>>((const float4*)xagg, W1, b1, (f16x2*)h0);

    // layers 2..4: fused Agg + MFMA GEMM (+bias, ReLU)
    const int fgrid = (N_NODES + 63) / 64;   // 1563
    k_aggemm<<<fgrid, 256, 0, stream>>>((const f16x2*)h0, rowptr, edges, dinv, Wp2, b2, h1);
    k_aggemm<<<fgrid, 256, 0, stream>>>((const f16x2*)h1, rowptr, edges, dinv, Wp3, b3, h0);
    k_aggemm<<<fgrid, 256, 0, stream>>>((const f16x2*)h0, rowptr, edges, dinv, Wp4, b4, h1);

    k_pool1 <<<N_GRAPH * POOL_SEG, 128, 0, stream>>>(h1, batch, parts);
    k_pool2h<<<N_GRAPH, 128, 0, stream>>>(parts, batch, Wl, bl, out);
}

// Round 6
// 519.410 us; speedup vs baseline: 1.2238x; 1.2238x over previous
//
#include <hip/hip_runtime.h>
#include <math.h>

#define N_NODES 100000
#define N_EDGES 1600000
#define F_IN    4
#define HID     128
#define N_CLS   5
#define N_GRAPH 256
#define POOL_SEG 8

typedef _Float16 f16;
typedef _Float16 f16x2 __attribute__((ext_vector_type(2)));
typedef _Float16 f16x4 __attribute__((ext_vector_type(4)));
typedef _Float16 f16x8 __attribute__((ext_vector_type(8)));
typedef float f32x4 __attribute__((ext_vector_type(4)));

// decode 4-byte edge record: [src:17 | coef-f16-positive:15]
__device__ __forceinline__ float rec_coef(unsigned r) {
    return (float)__builtin_bit_cast(_Float16, (unsigned short)(r & 0x7FFFu));
}

// ---------------- degree histogram over dst; atomic old value = edge rank within row --------
__global__ __launch_bounds__(256) void k_hist(const int* __restrict__ dst, int* __restrict__ deg,
                                              int* __restrict__ rank) {
    int e = blockIdx.x * 256 + threadIdx.x;
    if (e < N_EDGES) rank[e] = atomicAdd(&deg[dst[e]], 1);
}

// ---------------- exclusive scan (3-pass) ---------------
__global__ __launch_bounds__(256) void k_scan1(const int* __restrict__ cnt, int* __restrict__ excl,
                                               int* __restrict__ bsum) {
    __shared__ int s[256];
    int i = blockIdx.x * 256 + threadIdx.x;
    int v = (i < N_NODES) ? cnt[i] : 0;
    s[threadIdx.x] = v;
    __syncthreads();
    for (int off = 1; off < 256; off <<= 1) {
        int t = (threadIdx.x >= off) ? s[threadIdx.x - off] : 0;
        __syncthreads();
        s[threadIdx.x] += t;
        __syncthreads();
    }
    if (i < N_NODES) excl[i] = s[threadIdx.x] - v;
    if (threadIdx.x == 255) bsum[blockIdx.x] = s[255];
}

__global__ __launch_bounds__(512) void k_scan2(int* __restrict__ bsum, int nb) {
    __shared__ int s[512];
    int v = (threadIdx.x < nb) ? bsum[threadIdx.x] : 0;
    s[threadIdx.x] = v;
    __syncthreads();
    for (int off = 1; off < 512; off <<= 1) {
        int t = (threadIdx.x >= off) ? s[threadIdx.x - off] : 0;
        __syncthreads();
        s[threadIdx.x] += t;
        __syncthreads();
    }
    if (threadIdx.x < nb) bsum[threadIdx.x] = s[threadIdx.x] - v;
}

// scan3 + dinv fused
__global__ __launch_bounds__(256) void k_scan3(int* __restrict__ excl, const int* __restrict__ bsum,
                                               const int* __restrict__ deg, float* __restrict__ dinv) {
    int i = blockIdx.x * 256 + threadIdx.x;
    if (i < N_NODES) {
        excl[i] += bsum[blockIdx.x];
        dinv[i] = rsqrtf((float)deg[i] + 1.0f);
    }
    if (i == 0) excl[N_NODES] = N_EDGES;
}

// ---------------- CSR fill: no atomics; one 4B scattered write per edge ---------------
__global__ __launch_bounds__(256) void k_fill(const int* __restrict__ src, const int* __restrict__ dst,
                                              const int* __restrict__ rank,
                                              const int* __restrict__ rowptr,
                                              const float* __restrict__ dinv,
                                              unsigned* __restrict__ edges) {
    int e = blockIdx.x * 256 + threadIdx.x;
    if (e < N_EDGES) {
        int d = dst[e], s = src[e];
        int ppos = rowptr[d] + rank[e];
        float c = dinv[s] * dinv[d];
        unsigned short cb = __builtin_bit_cast(unsigned short, (f16)c);
        edges[ppos] = ((unsigned)s << 15) | (unsigned)(cb & 0x7FFFu);
    }
}

// ---------------- aggregate raw features x (N x 4) — Agg(x) before the layer-1 GEMM ----------
__global__ __launch_bounds__(256) void k_aggx(const float4* __restrict__ x, const int* __restrict__ rowptr,
                                              const unsigned* __restrict__ edges,
                                              const float* __restrict__ dinv, float4* __restrict__ out) {
    int i = blockIdx.x * 256 + threadIdx.x;
    if (i >= N_NODES) return;
    float di = dinv[i];
    float4 xv = x[i];
    float c0 = di * di;
    float ax = c0 * xv.x, ay = c0 * xv.y, az = c0 * xv.z, aw = c0 * xv.w;
    int beg = rowptr[i], end = rowptr[i + 1];
    for (int e = beg; e < end; ++e) {
        unsigned r = edges[e];
        float c = rec_coef(r);
        float4 v = x[r >> 15];
        ax = fmaf(c, v.x, ax); ay = fmaf(c, v.y, ay);
        az = fmaf(c, v.z, az); aw = fmaf(c, v.w, aw);
    }
    out[i] = make_float4(ax, ay, az, aw);
}

// ---------------- layer-1 GEMM: (N x 4) @ (4 x 128) + bias, ReLU, fp16 out ---------------
__global__ __launch_bounds__(256) void k_gemm4(const float4* __restrict__ A, const float* __restrict__ W,
                                               const float* __restrict__ bias, f16x2* __restrict__ out) {
    int idx = blockIdx.x * 256 + threadIdx.x;      // idx = i*64 + fpair
    int i = idx >> 6, fp = (idx & 63) * 2;
    float4 a = A[i];
    float v0 = bias[fp];
    v0 = fmaf(a.x, W[fp],           v0);
    v0 = fmaf(a.y, W[HID + fp],     v0);
    v0 = fmaf(a.z, W[2 * HID + fp], v0);
    v0 = fmaf(a.w, W[3 * HID + fp], v0);
    float v1 = bias[fp + 1];
    v1 = fmaf(a.x, W[fp + 1],           v1);
    v1 = fmaf(a.y, W[HID + fp + 1],     v1);
    v1 = fmaf(a.z, W[2 * HID + fp + 1], v1);
    v1 = fmaf(a.w, W[3 * HID + fp + 1], v1);
    f16x2 o;
    o.x = (f16)fmaxf(v0, 0.0f);
    o.y = (f16)fmaxf(v1, 0.0f);
    out[idx] = o;
}

// ---------------- CSR aggregation, fp16 payload: one wave per node, f16x2 per lane -----------
__global__ __launch_bounds__(256) void k_agg(const f16x2* __restrict__ h, const int* __restrict__ rowptr,
                                             const unsigned* __restrict__ edges,
                                             const float* __restrict__ dinv, f16x2* __restrict__ out) {
    int node = blockIdx.x * 4 + (threadIdx.x >> 6);
    if (node >= N_NODES) return;
    int lane = threadIdx.x & 63;
    int beg = rowptr[node], end = rowptr[node + 1];
    float di = dinv[node];
    f16x2 self = h[node * 64 + lane];
    float c0 = di * di;
    float accx = c0 * (float)self.x;
    float accy = c0 * (float)self.y;
    int e = beg;
    for (; e + 8 <= end; e += 8) {
        unsigned r0 = edges[e + 0], r1 = edges[e + 1], r2 = edges[e + 2], r3 = edges[e + 3];
        unsigned r4 = edges[e + 4], r5 = edges[e + 5], r6 = edges[e + 6], r7 = edges[e + 7];
        f16x2 v0 = h[(r0 >> 15) * 64 + lane], v1 = h[(r1 >> 15) * 64 + lane];
        f16x2 v2 = h[(r2 >> 15) * 64 + lane], v3 = h[(r3 >> 15) * 64 + lane];
        f16x2 v4 = h[(r4 >> 15) * 64 + lane], v5 = h[(r5 >> 15) * 64 + lane];
        f16x2 v6 = h[(r6 >> 15) * 64 + lane], v7 = h[(r7 >> 15) * 64 + lane];
        float c0f = rec_coef(r0), c1f = rec_coef(r1), c2f = rec_coef(r2), c3f = rec_coef(r3);
        float c4f = rec_coef(r4), c5f = rec_coef(r5), c6f = rec_coef(r6), c7f = rec_coef(r7);
        accx = fmaf(c0f, (float)v0.x, accx); accy = fmaf(c0f, (float)v0.y, accy);
        accx = fmaf(c1f, (float)v1.x, accx); accy = fmaf(c1f, (float)v1.y, accy);
        accx = fmaf(c2f, (float)v2.x, accx); accy = fmaf(c2f, (float)v2.y, accy);
        accx = fmaf(c3f, (float)v3.x, accx); accy = fmaf(c3f, (float)v3.y, accy);
        accx = fmaf(c4f, (float)v4.x, accx); accy = fmaf(c4f, (float)v4.y, accy);
        accx = fmaf(c5f, (float)v5.x, accx); accy = fmaf(c5f, (float)v5.y, accy);
        accx = fmaf(c6f, (float)v6.x, accx); accy = fmaf(c6f, (float)v6.y, accy);
        accx = fmaf(c7f, (float)v7.x, accx); accy = fmaf(c7f, (float)v7.y, accy);
    }
    for (; e < end; ++e) {
        unsigned r = edges[e];
        f16x2 v = h[(r >> 15) * 64 + lane];
        float c = rec_coef(r);
        accx = fmaf(c, (float)v.x, accx);
        accy = fmaf(c, (float)v.y, accy);
    }
    f16x2 o;
    o.x = (f16)accx;
    o.y = (f16)accy;
    out[node * 64 + lane] = o;
}

// ---------------- pack 3x W (128x128 fp32) into MFMA B-fragment order, fp16, one launch -----
// Wp[w][((ct*4 + ks)*64 + lane)*8 + j] = W[ks*32 + (lane>>4)*8 + j][ct*16 + (lane&15)]
__global__ __launch_bounds__(256) void k_packW3(const float* __restrict__ W2, const float* __restrict__ W3,
                                                const float* __restrict__ W4, f16* __restrict__ Wp) {
    int idx = blockIdx.x * 256 + threadIdx.x;   // 192 blocks x 256 = 49152 = 3 * 16384
    int which = idx >> 14;
    int r = idx & 16383;
    const float* W = (which == 0) ? W2 : (which == 1) ? W3 : W4;
    int j  = r & 7;
    int L  = (r >> 3) & 63;
    int ks = (r >> 9) & 3;
    int ct = r >> 11;
    int k = ks * 32 + (L >> 4) * 8 + j;
    int n = ct * 16 + (L & 15);
    Wp[idx] = (f16)W[k * HID + n];
}

// ---------------- main GEMM via MFMA: (N x 128 f16) @ Wp + bias, ReLU, f16 out ---------------
// Wave handles 16 rows x 128 cols. A-frag: lane holds A[row0 + (lane&15)][ks*32 + (lane>>4)*8 + j].
// C/D: col = lane&15 (+16*tile), row = (lane>>4)*4 + reg.
__global__ __launch_bounds__(256) void k_gemm_mfma(const f16* __restrict__ A, const f16* __restrict__ Wp,
                                                   const float* __restrict__ bias, f16* __restrict__ out) {
    int wave = threadIdx.x >> 6;
    int lane = threadIdx.x & 63;
    int row0 = blockIdx.x * 64 + wave * 16;
    if (row0 >= N_NODES) return;
    int m = lane & 15;
    int q = lane >> 4;
    const f16* Arow = A + (size_t)(row0 + m) * HID + q * 8;

    f32x4 acc[8];
#pragma unroll
    for (int t = 0; t < 8; ++t) acc[t] = (f32x4){0.f, 0.f, 0.f, 0.f};

#pragma unroll
    for (int ks = 0; ks < 4; ++ks) {
        f16x8 a = *(const f16x8*)(Arow + ks * 32);
#pragma unroll
        for (int t = 0; t < 8; ++t) {
            f16x8 b = *(const f16x8*)(Wp + ((size_t)(t * 4 + ks) * 64 + lane) * 8);
            acc[t] = __builtin_amdgcn_mfma_f32_16x16x32_f16(a, b, acc[t], 0, 0, 0);
        }
    }

    int orow = row0 + q * 4;
#pragma unroll
    for (int t = 0; t < 8; ++t) {
        float bb = bias[t * 16 + m];
#pragma unroll
        for (int r = 0; r < 4; ++r) {
            out[(size_t)(orow + r) * HID + t * 16 + m] = (f16)fmaxf(acc[t][r] + bb, 0.0f);
        }
    }
}

// ---------------- pooling pass 1: per (graph, segment) partial sums, fp32, deterministic -----
__device__ __forceinline__ int lower_bound_batch(const int* __restrict__ batch, int val) {
    int lo = 0, hi = N_NODES;
    while (lo < hi) { int m = (lo + hi) >> 1; if (batch[m] < val) lo = m + 1; else hi = m; }
    return lo;
}

__global__ __launch_bounds__(128) void k_pool1(const f16* __restrict__ h, const int* __restrict__ batch,
                                               float* __restrict__ partials) {
    int g = blockIdx.x / POOL_SEG;
    int s = blockIdx.x % POOL_SEG;
    int f = threadIdx.x;
    int beg = lower_bound_batch(batch, g);
    int end = lower_bound_batch(batch, g + 1);
    int len = end - beg;
    int sb = beg + (int)(((long long)len * s) / POOL_SEG);
    int se = beg + (int)(((long long)len * (s + 1)) / POOL_SEG);
    float acc = 0.0f;
    for (int i = sb; i < se; ++i) acc += (float)h[i * HID + f];
    partials[(size_t)blockIdx.x * HID + f] = acc;
}

// ---------------- pooling pass 2 + head fused ---------------
__global__ __launch_bounds__(128) void k_pool2h(const float* __restrict__ partials,
                                                const int* __restrict__ batch,
                                                const float* __restrict__ Wl, const float* __restrict__ bl,
                                                float* __restrict__ out) {
    __shared__ float sp[HID];
    int g = blockIdx.x;
    int f = threadIdx.x;
    float acc = 0.0f;
#pragma unroll
    for (int s = 0; s < POOL_SEG; ++s)
        acc += partials[(size_t)(g * POOL_SEG + s) * HID + f];
    int beg = lower_bound_batch(batch, g);
    int end = lower_bound_batch(batch, g + 1);
    sp[f] = acc / fmaxf((float)(end - beg), 1.0f);
    __syncthreads();
    if (f < N_CLS) {
        float v = bl[f];
        for (int k = 0; k < HID; ++k) v = fmaf(sp[k], Wl[k * N_CLS + f], v);
        out[g * N_CLS + f] = 1.0f / (1.0f + expf(-v));
    }
}

extern "C" void kernel_launch(void* const* d_in, const int* in_sizes, int n_in,
                              void* d_out, int out_size, void* d_ws, size_t ws_size,
                              hipStream_t stream) {
    const float* x     = (const float*)d_in[0];
    const int*   ei    = (const int*)d_in[1];
    const int*   batch = (const int*)d_in[2];
    const float* W1 = (const float*)d_in[3];  const float* b1 = (const float*)d_in[4];
    const float* W2 = (const float*)d_in[5];  const float* b2 = (const float*)d_in[6];
    const float* W3 = (const float*)d_in[7];  const float* b3 = (const float*)d_in[8];
    const float* W4 = (const float*)d_in[9];  const float* b4 = (const float*)d_in[10];
    const float* Wl = (const float*)d_in[11]; const float* bl = (const float*)d_in[12];
    float* out = (float*)d_out;

    char* p = (char*)d_ws;
    auto alloc = [&](size_t bytes) { char* r = p; p += (bytes + 255) & ~(size_t)255; return (void*)r; };
    int*      deg    = (int*)     alloc((size_t)N_NODES * 4);
    int*      rowptr = (int*)     alloc((size_t)(N_NODES + 1) * 4);
    int*      rank   = (int*)     alloc((size_t)N_EDGES * 4);
    int*      bsum   = (int*)     alloc(512 * 4);
    float*    dinv   = (float*)   alloc((size_t)N_NODES * 4);
    unsigned* edges  = (unsigned*)alloc((size_t)N_EDGES * 4);
    float*    xagg   = (float*)   alloc((size_t)N_NODES * F_IN * 4);
    f16*      h0     = (f16*)     alloc((size_t)N_NODES * HID * 2);
    f16*      h1     = (f16*)     alloc((size_t)N_NODES * HID * 2);
    float*    parts  = (float*)   alloc((size_t)N_GRAPH * POOL_SEG * HID * 4);
    f16*      Wp     = (f16*)     alloc((size_t)3 * HID * HID * 2);
    f16*      Wp2 = Wp;
    f16*      Wp3 = Wp + HID * HID;
    f16*      Wp4 = Wp + 2 * HID * HID;

    const int* srcv = ei;              // edge_index[0]
    const int* dstv = ei + N_EDGES;    // edge_index[1]

    hipMemsetAsync(deg, 0, (size_t)N_NODES * 4, stream);

    const int nb = (N_NODES + 255) / 256;   // 391

    k_hist  <<<N_EDGES / 256, 256, 0, stream>>>(dstv, deg, rank);
    k_scan1 <<<nb, 256, 0, stream>>>(deg, rowptr, bsum);
    k_scan2 <<<1, 512, 0, stream>>>(bsum, nb);
    k_scan3 <<<nb, 256, 0, stream>>>(rowptr, bsum, deg, dinv);
    k_fill  <<<N_EDGES / 256, 256, 0, stream>>>(srcv, dstv, rank, rowptr, dinv, edges);
    k_packW3<<<192, 256, 0, stream>>>(W2, W3, W4, Wp);

    // layer 1: Agg(x) @ W1  (aggregate the 4-wide features, then expand to 128)
    k_aggx <<<nb, 256, 0, stream>>>((const float4*)x, rowptr, edges, dinv, (float4*)xagg);
    k_gemm4<<<(N_NODES * 64) / 256, 256, 0, stream>>>((const float4*)xagg, W1, b1, (f16x2*)h0);

    // layers 2..4: Agg (wave-per-node, max TLP) then MFMA GEMM (+bias, ReLU)
    const int ggrid = (N_NODES + 63) / 64;   // 1563
    k_agg      <<<N_NODES / 4, 256, 0, stream>>>((const f16x2*)h0, rowptr, edges, dinv, (f16x2*)h1);
    k_gemm_mfma<<<ggrid, 256, 0, stream>>>(h1, Wp2, b2, h0);
    k_agg      <<<N_NODES / 4, 256, 0, stream>>>((const f16x2*)h0, rowptr, edges, dinv, (f16x2*)h1);
    k_gemm_mfma<<<ggrid, 256, 0, stream>>>(h1, Wp3, b3, h0);
    k_agg      <<<N_NODES / 4, 256, 0, stream>>>((const f16x2*)h0, rowptr, edges, dinv, (f16x2*)h1);
    k_gemm_mfma<<<ggrid, 256, 0, stream>>>(h1, Wp4, b4, h0);

    k_pool1 <<<N_GRAPH * POOL_SEG, 128, 0, stream>>>(h0, batch, parts);
    k_pool2h<<<N_GRAPH, 128, 0, stream>>>(parts, batch, Wl, bl, out);
}

// Round 7
// 480.515 us; speedup vs baseline: 1.3229x; 1.0809x over previous
//
#include <hip/hip_runtime.h>
#include <hip/hip_fp8.h>
#include <math.h>

#define N_NODES 100000
#define N_EDGES 1600000
#define F_IN    4
#define HID     128
#define N_CLS   5
#define N_GRAPH 256
#define POOL_SEG 8

typedef _Float16 f16;
typedef _Float16 f16x2 __attribute__((ext_vector_type(2)));
typedef _Float16 f16x8 __attribute__((ext_vector_type(8)));
typedef float f32x4 __attribute__((ext_vector_type(4)));

// decode 4-byte edge record: [src:17 | coef-f16-positive:15]
__device__ __forceinline__ float rec_coef(unsigned r) {
    return (float)__builtin_bit_cast(_Float16, (unsigned short)(r & 0x7FFFu));
}

__device__ __forceinline__ float2 fp8x2_to_f32x2(unsigned short raw) {
    __hip_fp8x2_e4m3 t;
    t.__x = raw;
    return static_cast<float2>(t);
}

// ---------------- degree histogram over dst; atomic old value = edge rank within row --------
__global__ __launch_bounds__(256) void k_hist(const int* __restrict__ dst, int* __restrict__ deg,
                                              int* __restrict__ rank) {
    int e = blockIdx.x * 256 + threadIdx.x;
    if (e < N_EDGES) rank[e] = atomicAdd(&deg[dst[e]], 1);
}

// ---------------- exclusive scan (3-pass) ---------------
__global__ __launch_bounds__(256) void k_scan1(const int* __restrict__ cnt, int* __restrict__ excl,
                                               int* __restrict__ bsum) {
    __shared__ int s[256];
    int i = blockIdx.x * 256 + threadIdx.x;
    int v = (i < N_NODES) ? cnt[i] : 0;
    s[threadIdx.x] = v;
    __syncthreads();
    for (int off = 1; off < 256; off <<= 1) {
        int t = (threadIdx.x >= off) ? s[threadIdx.x - off] : 0;
        __syncthreads();
        s[threadIdx.x] += t;
        __syncthreads();
    }
    if (i < N_NODES) excl[i] = s[threadIdx.x] - v;
    if (threadIdx.x == 255) bsum[blockIdx.x] = s[255];
}

__global__ __launch_bounds__(512) void k_scan2(int* __restrict__ bsum, int nb) {
    __shared__ int s[512];
    int v = (threadIdx.x < nb) ? bsum[threadIdx.x] : 0;
    s[threadIdx.x] = v;
    __syncthreads();
    for (int off = 1; off < 512; off <<= 1) {
        int t = (threadIdx.x >= off) ? s[threadIdx.x - off] : 0;
        __syncthreads();
        s[threadIdx.x] += t;
        __syncthreads();
    }
    if (threadIdx.x < nb) bsum[threadIdx.x] = s[threadIdx.x] - v;
}

// scan3 + dinv fused
__global__ __launch_bounds__(256) void k_scan3(int* __restrict__ excl, const int* __restrict__ bsum,
                                               const int* __restrict__ deg, float* __restrict__ dinv) {
    int i = blockIdx.x * 256 + threadIdx.x;
    if (i < N_NODES) {
        excl[i] += bsum[blockIdx.x];
        dinv[i] = rsqrtf((float)deg[i] + 1.0f);
    }
    if (i == 0) excl[N_NODES] = N_EDGES;
}

// ---------------- CSR fill: no atomics; one 4B scattered write per edge ---------------
__global__ __launch_bounds__(256) void k_fill(const int* __restrict__ src, const int* __restrict__ dst,
                                              const int* __restrict__ rank,
                                              const int* __restrict__ rowptr,
                                              const float* __restrict__ dinv,
                                              unsigned* __restrict__ edges) {
    int e = blockIdx.x * 256 + threadIdx.x;
    if (e < N_EDGES) {
        int d = dst[e], s = src[e];
        int ppos = rowptr[d] + rank[e];
        float c = dinv[s] * dinv[d];
        unsigned short cb = __builtin_bit_cast(unsigned short, (f16)c);
        edges[ppos] = ((unsigned)s << 15) | (unsigned)(cb & 0x7FFFu);
    }
}

// ---------------- FUSED layer 1: Agg(x) (thread-per-node) + (Nx4)@(4x128) GEMM, fp8 out -----
__global__ __launch_bounds__(256) void k_aggxg(const float4* __restrict__ x,
                                               const int* __restrict__ rowptr,
                                               const unsigned* __restrict__ edges,
                                               const float* __restrict__ dinv,
                                               const float* __restrict__ W1, const float* __restrict__ b1,
                                               unsigned* __restrict__ hA /* fp8 rows, as u32 */) {
    __shared__ float4 sx[256];
    __shared__ float sW[4 * HID];
    __shared__ float sb[HID];
    int tid = threadIdx.x;
    sW[tid] = W1[tid];
    sW[tid + 256] = W1[tid + 256];
    if (tid < HID) sb[tid] = b1[tid];

    int i = blockIdx.x * 256 + tid;
    float4 agg = make_float4(0.f, 0.f, 0.f, 0.f);
    if (i < N_NODES) {
        float di = dinv[i];
        float4 xv = x[i];
        float c0 = di * di;
        agg.x = c0 * xv.x; agg.y = c0 * xv.y; agg.z = c0 * xv.z; agg.w = c0 * xv.w;
        int beg = rowptr[i], end = rowptr[i + 1];
        for (int e = beg; e < end; ++e) {
            unsigned r = edges[e];
            float c = rec_coef(r);
            float4 v = x[r >> 15];
            agg.x = fmaf(c, v.x, agg.x); agg.y = fmaf(c, v.y, agg.y);
            agg.z = fmaf(c, v.z, agg.z); agg.w = fmaf(c, v.w, agg.w);
        }
    }
    sx[tid] = agg;
    __syncthreads();

    int node0 = blockIdx.x * 256;
#pragma unroll
    for (int it = 0; it < 32; ++it) {
        int id = it * 256 + tid;
        int n = id >> 5;          // local node 0..255
        int g = id & 31;          // column group (4 cols)
        int node = node0 + n;
        if (node >= N_NODES) continue;
        float4 a = sx[n];
        float c[4];
#pragma unroll
        for (int j = 0; j < 4; ++j) {
            int col = g * 4 + j;
            float v = sb[col];
            v = fmaf(a.x, sW[col],           v);
            v = fmaf(a.y, sW[HID + col],     v);
            v = fmaf(a.z, sW[2 * HID + col], v);
            v = fmaf(a.w, sW[3 * HID + col], v);
            c[j] = fmaxf(v, 0.0f);
        }
        unsigned lo = __hip_fp8x2_e4m3(make_float2(c[0], c[1])).__x;
        unsigned hi = __hip_fp8x2_e4m3(make_float2(c[2], c[3])).__x;
        hA[node * 32 + g] = lo | (hi << 16);
    }
}

// ---------------- CSR aggregation, fp8 payload: one wave per node, fp8x2 per lane ------------
__global__ __launch_bounds__(256) void k_agg8(const unsigned short* __restrict__ h8,
                                              const int* __restrict__ rowptr,
                                              const unsigned* __restrict__ edges,
                                              const float* __restrict__ dinv,
                                              f16x2* __restrict__ out) {
    int node = blockIdx.x * 4 + (threadIdx.x >> 6);
    if (node >= N_NODES) return;
    int lane = threadIdx.x & 63;
    int beg = rowptr[node], end = rowptr[node + 1];
    float di = dinv[node];
    float2 self = fp8x2_to_f32x2(h8[node * 64 + lane]);
    float c0 = di * di;
    float accx = c0 * self.x;
    float accy = c0 * self.y;
    int e = beg;
    for (; e + 8 <= end; e += 8) {
        unsigned r0 = edges[e + 0], r1 = edges[e + 1], r2 = edges[e + 2], r3 = edges[e + 3];
        unsigned r4 = edges[e + 4], r5 = edges[e + 5], r6 = edges[e + 6], r7 = edges[e + 7];
        unsigned short w0 = h8[(r0 >> 15) * 64 + lane], w1 = h8[(r1 >> 15) * 64 + lane];
        unsigned short w2 = h8[(r2 >> 15) * 64 + lane], w3 = h8[(r3 >> 15) * 64 + lane];
        unsigned short w4 = h8[(r4 >> 15) * 64 + lane], w5 = h8[(r5 >> 15) * 64 + lane];
        unsigned short w6 = h8[(r6 >> 15) * 64 + lane], w7 = h8[(r7 >> 15) * 64 + lane];
        float2 v0 = fp8x2_to_f32x2(w0), v1 = fp8x2_to_f32x2(w1);
        float2 v2 = fp8x2_to_f32x2(w2), v3 = fp8x2_to_f32x2(w3);
        float2 v4 = fp8x2_to_f32x2(w4), v5 = fp8x2_to_f32x2(w5);
        float2 v6 = fp8x2_to_f32x2(w6), v7 = fp8x2_to_f32x2(w7);
        float c0f = rec_coef(r0), c1f = rec_coef(r1), c2f = rec_coef(r2), c3f = rec_coef(r3);
        float c4f = rec_coef(r4), c5f = rec_coef(r5), c6f = rec_coef(r6), c7f = rec_coef(r7);
        accx = fmaf(c0f, v0.x, accx); accy = fmaf(c0f, v0.y, accy);
        accx = fmaf(c1f, v1.x, accx); accy = fmaf(c1f, v1.y, accy);
        accx = fmaf(c2f, v2.x, accx); accy = fmaf(c2f, v2.y, accy);
        accx = fmaf(c3f, v3.x, accx); accy = fmaf(c3f, v3.y, accy);
        accx = fmaf(c4f, v4.x, accx); accy = fmaf(c4f, v4.y, accy);
        accx = fmaf(c5f, v5.x, accx); accy = fmaf(c5f, v5.y, accy);
        accx = fmaf(c6f, v6.x, accx); accy = fmaf(c6f, v6.y, accy);
        accx = fmaf(c7f, v7.x, accx); accy = fmaf(c7f, v7.y, accy);
    }
    for (; e < end; ++e) {
        unsigned r = edges[e];
        float2 v = fp8x2_to_f32x2(h8[(r >> 15) * 64 + lane]);
        float c = rec_coef(r);
        accx = fmaf(c, v.x, accx);
        accy = fmaf(c, v.y, accy);
    }
    f16x2 o;
    o.x = (f16)accx;
    o.y = (f16)accy;
    out[node * 64 + lane] = o;
}

// ---------------- pack 3x W (128x128 fp32) into MFMA B-fragment order, fp16, one launch -----
__global__ __launch_bounds__(256) void k_packW3(const float* __restrict__ W2, const float* __restrict__ W3,
                                                const float* __restrict__ W4, f16* __restrict__ Wp) {
    int idx = blockIdx.x * 256 + threadIdx.x;   // 192 blocks x 256 = 49152 = 3 * 16384
    int which = idx >> 14;
    int r = idx & 16383;
    const float* W = (which == 0) ? W2 : (which == 1) ? W3 : W4;
    int j  = r & 7;
    int L  = (r >> 3) & 63;
    int ks = (r >> 9) & 3;
    int ct = r >> 11;
    int k = ks * 32 + (L >> 4) * 8 + j;
    int n = ct * 16 + (L & 15);
    Wp[idx] = (f16)W[k * HID + n];
}

// ---------------- main GEMM via MFMA: (N x 128 f16) @ Wp + bias, ReLU; fp8 or fp16 out -------
template <bool FP8OUT>
__global__ __launch_bounds__(256) void k_gemm_mfma(const f16* __restrict__ A, const f16* __restrict__ Wp,
                                                   const float* __restrict__ bias, void* __restrict__ outv) {
    int wave = threadIdx.x >> 6;
    int lane = threadIdx.x & 63;
    int row0 = blockIdx.x * 64 + wave * 16;
    if (row0 >= N_NODES) return;
    int m = lane & 15;
    int q = lane >> 4;
    const f16* Arow = A + (size_t)(row0 + m) * HID + q * 8;

    f32x4 acc[8];
#pragma unroll
    for (int t = 0; t < 8; ++t) acc[t] = (f32x4){0.f, 0.f, 0.f, 0.f};

#pragma unroll
    for (int ks = 0; ks < 4; ++ks) {
        f16x8 a = *(const f16x8*)(Arow + ks * 32);
#pragma unroll
        for (int t = 0; t < 8; ++t) {
            f16x8 b = *(const f16x8*)(Wp + ((size_t)(t * 4 + ks) * 64 + lane) * 8);
            acc[t] = __builtin_amdgcn_mfma_f32_16x16x32_f16(a, b, acc[t], 0, 0, 0);
        }
    }

    int orow = row0 + q * 4;
#pragma unroll
    for (int t = 0; t < 8; ++t) {
        float bb = bias[t * 16 + m];
#pragma unroll
        for (int r = 0; r < 4; ++r) {
            float val = fmaxf(acc[t][r] + bb, 0.0f);
            if constexpr (FP8OUT) {
                __hip_fp8_e4m3* out8 = (__hip_fp8_e4m3*)outv;
                out8[(size_t)(orow + r) * HID + t * 16 + m] = __hip_fp8_e4m3(val);
            } else {
                f16* out = (f16*)outv;
                out[(size_t)(orow + r) * HID + t * 16 + m] = (f16)val;
            }
        }
    }
}

// ---------------- pooling pass 1: per (graph, segment) partial sums, fp32, deterministic -----
__device__ __forceinline__ int lower_bound_batch(const int* __restrict__ batch, int val) {
    int lo = 0, hi = N_NODES;
    while (lo < hi) { int m = (lo + hi) >> 1; if (batch[m] < val) lo = m + 1; else hi = m; }
    return lo;
}

__global__ __launch_bounds__(128) void k_pool1(const f16* __restrict__ h, const int* __restrict__ batch,
                                               float* __restrict__ partials) {
    int g = blockIdx.x / POOL_SEG;
    int s = blockIdx.x % POOL_SEG;
    int f = threadIdx.x;
    int beg = lower_bound_batch(batch, g);
    int end = lower_bound_batch(batch, g + 1);
    int len = end - beg;
    int sb = beg + (int)(((long long)len * s) / POOL_SEG);
    int se = beg + (int)(((long long)len * (s + 1)) / POOL_SEG);
    float acc = 0.0f;
    for (int i = sb; i < se; ++i) acc += (float)h[i * HID + f];
    partials[(size_t)blockIdx.x * HID + f] = acc;
}

// ---------------- pooling pass 2 + head fused ---------------
__global__ __launch_bounds__(128) void k_pool2h(const float* __restrict__ partials,
                                                const int* __restrict__ batch,
                                                const float* __restrict__ Wl, const float* __restrict__ bl,
                                                float* __restrict__ out) {
    __shared__ float sp[HID];
    int g = blockIdx.x;
    int f = threadIdx.x;
    float acc = 0.0f;
#pragma unroll
    for (int s = 0; s < POOL_SEG; ++s)
        acc += partials[(size_t)(g * POOL_SEG + s) * HID + f];
    int beg = lower_bound_batch(batch, g);
    int end = lower_bound_batch(batch, g + 1);
    sp[f] = acc / fmaxf((float)(end - beg), 1.0f);
    __syncthreads();
    if (f < N_CLS) {
        float v = bl[f];
        for (int k = 0; k < HID; ++k) v = fmaf(sp[k], Wl[k * N_CLS + f], v);
        out[g * N_CLS + f] = 1.0f / (1.0f + expf(-v));
    }
}

extern "C" void kernel_launch(void* const* d_in, const int* in_sizes, int n_in,
                              void* d_out, int out_size, void* d_ws, size_t ws_size,
                              hipStream_t stream) {
    const float* x     = (const float*)d_in[0];
    const int*   ei    = (const int*)d_in[1];
    const int*   batch = (const int*)d_in[2];
    const float* W1 = (const float*)d_in[3];  const float* b1 = (const float*)d_in[4];
    const float* W2 = (const float*)d_in[5];  const float* b2 = (const float*)d_in[6];
    const float* W3 = (const float*)d_in[7];  const float* b3 = (const float*)d_in[8];
    const float* W4 = (const float*)d_in[9];  const float* b4 = (const float*)d_in[10];
    const float* Wl = (const float*)d_in[11]; const float* bl = (const float*)d_in[12];
    float* out = (float*)d_out;

    char* p = (char*)d_ws;
    auto alloc = [&](size_t bytes) { char* r = p; p += (bytes + 255) & ~(size_t)255; return (void*)r; };
    int*      deg    = (int*)     alloc((size_t)N_NODES * 4);
    int*      rowptr = (int*)     alloc((size_t)(N_NODES + 1) * 4);
    int*      rank   = (int*)     alloc((size_t)N_EDGES * 4);
    int*      bsum   = (int*)     alloc(512 * 4);
    float*    dinv   = (float*)   alloc((size_t)N_NODES * 4);
    unsigned* edges  = (unsigned*)alloc((size_t)N_EDGES * 4);
    unsigned* hA     = (unsigned*)alloc((size_t)N_NODES * HID);      // fp8 gather source
    f16*      hB     = (f16*)     alloc((size_t)N_NODES * HID * 2);  // fp16 agg out / GEMM A
    f16*      h4     = (f16*)     alloc((size_t)N_NODES * HID * 2);  // fp16 final layer out
    float*    parts  = (float*)   alloc((size_t)N_GRAPH * POOL_SEG * HID * 4);
    f16*      Wp     = (f16*)     alloc((size_t)3 * HID * HID * 2);
    f16*      Wp2 = Wp;
    f16*      Wp3 = Wp + HID * HID;
    f16*      Wp4 = Wp + 2 * HID * HID;

    const int* srcv = ei;              // edge_index[0]
    const int* dstv = ei + N_EDGES;    // edge_index[1]

    hipMemsetAsync(deg, 0, (size_t)N_NODES * 4, stream);

    const int nb = (N_NODES + 255) / 256;   // 391

    k_hist  <<<N_EDGES / 256, 256, 0, stream>>>(dstv, deg, rank);
    k_scan1 <<<nb, 256, 0, stream>>>(deg, rowptr, bsum);
    k_scan2 <<<1, 512, 0, stream>>>(bsum, nb);
    k_scan3 <<<nb, 256, 0, stream>>>(rowptr, bsum, deg, dinv);
    k_fill  <<<N_EDGES / 256, 256, 0, stream>>>(srcv, dstv, rank, rowptr, dinv, edges);
    k_packW3<<<192, 256, 0, stream>>>(W2, W3, W4, Wp);

    // layer 1: fused Agg(x) + (Nx4)@(4x128) GEMM, fp8 out
    k_aggxg<<<nb, 256, 0, stream>>>((const float4*)x, rowptr, edges, dinv, W1, b1, hA);

    // layers 2..4: Agg (fp8 gather, wave-per-node) then MFMA GEMM (+bias, ReLU)
    const int ggrid = (N_NODES + 63) / 64;   // 1563
    k_agg8<<<N_NODES / 4, 256, 0, stream>>>((const unsigned short*)hA, rowptr, edges, dinv, (f16x2*)hB);
    k_gemm_mfma<true ><<<ggrid, 256, 0, stream>>>(hB, Wp2, b2, hA);
    k_agg8<<<N_NODES / 4, 256, 0, stream>>>((const unsigned short*)hA, rowptr, edges, dinv, (f16x2*)hB);
    k_gemm_mfma<true ><<<ggrid, 256, 0, stream>>>(hB, Wp3, b3, hA);
    k_agg8<<<N_NODES / 4, 256, 0, stream>>>((const unsigned short*)hA, rowptr, edges, dinv, (f16x2*)hB);
    k_gemm_mfma<false><<<ggrid, 256, 0, stream>>>(hB, Wp4, b4, h4);

    k_pool1 <<<N_GRAPH * POOL_SEG, 128, 0, stream>>>(h4, batch, parts);
    k_pool2h<<<N_GRAPH, 128, 0, stream>>>(parts, batch, Wl, bl, out);
}

// Round 8
// 448.955 us; speedup vs baseline: 1.4159x; 1.0703x over previous
//
#include <hip/hip_runtime.h>
#include <hip/hip_fp8.h>
#include <math.h>

#define N_NODES 100000
#define N_EDGES 1600000
#define F_IN    4
#define HID     128
#define N_CLS   5
#define N_GRAPH 256
#define POOL_SEG 8

#define BSHIFT   9
#define BSIZE    512
#define NBUK     196            // ceil(100000 / 512)
#define NCHUNK   200
#define CHUNK    8000           // 200 * 8000 = 1.6M exactly

typedef _Float16 f16;
typedef _Float16 f16x2 __attribute__((ext_vector_type(2)));
typedef _Float16 f16x8 __attribute__((ext_vector_type(8)));
typedef float f32x4 __attribute__((ext_vector_type(4)));

// decode 4-byte edge record: [src:17 | coef-f16-positive:15]
__device__ __forceinline__ float rec_coef(unsigned r) {
    return (float)__builtin_bit_cast(_Float16, (unsigned short)(r & 0x7FFFu));
}

__device__ __forceinline__ float2 fp8x2_to_f32x2(unsigned short raw) {
    __hip_fp8x2_e4m3 t;
    t.__x = raw;
    return static_cast<float2>(t);
}

// ---------------- CSR build step 1: per-(chunk,bucket) counts via LDS histogram -------------
__global__ __launch_bounds__(256) void k_bc(const int* __restrict__ dst, int* __restrict__ C) {
    __shared__ int cnt[NBUK];
    int t = threadIdx.x;
    if (t < NBUK) cnt[t] = 0;
    __syncthreads();
    int base = blockIdx.x * CHUNK;
#pragma unroll
    for (int it = 0; it < 32; ++it) {
        int idx = it * 256 + t;
        if (idx < CHUNK) atomicAdd(&cnt[dst[base + idx] >> BSHIFT], 1);
    }
    __syncthreads();
    if (t < NBUK) C[blockIdx.x * NBUK + t] = cnt[t];
}

// ---------------- step 2: offsets. Off[c][b] = prefix over chunks; bbase = bucket bases -----
__global__ __launch_bounds__(256) void k_bscan(const int* __restrict__ C, int* __restrict__ Off,
                                               int* __restrict__ bbase, int* __restrict__ rowptr) {
    __shared__ int s[256];
    int b = threadIdx.x;
    int tot = 0;
    if (b < NBUK) {
        for (int c = 0; c < NCHUNK; ++c) {
            Off[c * NBUK + b] = tot;
            tot += C[c * NBUK + b];
        }
    }
    s[b] = (b < NBUK) ? tot : 0;
    __syncthreads();
    for (int off = 1; off < 256; off <<= 1) {
        int v = (b >= off) ? s[b - off] : 0;
        __syncthreads();
        s[b] += v;
        __syncthreads();
    }
    if (b < NBUK) bbase[b] = s[b] - tot;   // exclusive
    if (b == 0) { bbase[NBUK] = N_EDGES; rowptr[N_NODES] = N_EDGES; }
}

// ---------------- step 3: scatter packed records into bucket-grouped array ------------------
// record: (src:17)<<9 | (dst & 511)
__global__ __launch_bounds__(256) void k_scatter(const int* __restrict__ src, const int* __restrict__ dst,
                                                 const int* __restrict__ Off, const int* __restrict__ bbase,
                                                 unsigned* __restrict__ bkt) {
    __shared__ int cur[NBUK];
    int t = threadIdx.x;
    if (t < NBUK) cur[t] = bbase[t] + Off[blockIdx.x * NBUK + t];
    __syncthreads();
    int base = blockIdx.x * CHUNK;
#pragma unroll
    for (int it = 0; it < 32; ++it) {
        int idx = it * 256 + t;
        if (idx < CHUNK) {
            int s = src[base + idx], d = dst[base + idx];
            int b = d >> BSHIFT;
            int p = atomicAdd(&cur[b], 1);
            bkt[p] = ((unsigned)s << BSHIFT) | (unsigned)(d & (BSIZE - 1));
        }
    }
}

// ---------------- step 4: per-bucket local CSR (hist -> scan -> scatter), rowptr + dinv -----
__global__ __launch_bounds__(256) void k_local(const unsigned* __restrict__ bkt,
                                               const int* __restrict__ bbase,
                                               int* __restrict__ rowptr, float* __restrict__ dinv,
                                               int* __restrict__ csrSrc) {
    __shared__ int hist[BSIZE], sc[BSIZE], cur[BSIZE];
    int t = threadIdx.x;
    int b = blockIdx.x;
    int s0 = bbase[b], s1 = bbase[b + 1];
    hist[t] = 0; hist[t + 256] = 0;
    __syncthreads();
    for (int e = s0 + t; e < s1; e += 256) atomicAdd(&hist[bkt[e] & (BSIZE - 1)], 1);
    __syncthreads();
    sc[t] = hist[t]; sc[t + 256] = hist[t + 256];
    __syncthreads();
    for (int off = 1; off < BSIZE; off <<= 1) {
        int i0 = t, i1 = t + 256;
        int v0 = (i0 >= off) ? sc[i0 - off] : 0;
        int v1 = (i1 >= off) ? sc[i1 - off] : 0;
        __syncthreads();
        sc[i0] += v0; sc[i1] += v1;
        __syncthreads();
    }
#pragma unroll
    for (int h = 0; h < 2; ++h) {
        int l = t + h * 256;
        int excl = sc[l] - hist[l];
        int node = b * BSIZE + l;
        if (node < N_NODES) {
            rowptr[node] = s0 + excl;
            dinv[node] = rsqrtf((float)hist[l] + 1.0f);
        }
        cur[l] = s0 + excl;
    }
    __syncthreads();
    for (int e = s0 + t; e < s1; e += 256) {
        unsigned r = bkt[e];
        int d = r & (BSIZE - 1);
        int p = atomicAdd(&cur[d], 1);
        csrSrc[p] = (int)(r >> BSHIFT);
    }
}

// ---------------- step 5: attach coefficients, emit final edge records ----------------------
__global__ __launch_bounds__(256) void k_coef(const int* __restrict__ csrSrc,
                                              const int* __restrict__ rowptr,
                                              const float* __restrict__ dinv,
                                              unsigned* __restrict__ edges) {
    int i = blockIdx.x * 256 + threadIdx.x;
    if (i >= N_NODES) return;
    float di = dinv[i];
    int beg = rowptr[i], end = rowptr[i + 1];
    for (int e = beg; e < end; ++e) {
        int s = csrSrc[e];
        float c = di * dinv[s];
        unsigned short cb = __builtin_bit_cast(unsigned short, (f16)c);
        edges[e] = ((unsigned)s << 15) | (unsigned)(cb & 0x7FFFu);
    }
}

// ---------------- FUSED layer 1: Agg(x) (thread-per-node) + (Nx4)@(4x128) GEMM, fp8 out -----
__global__ __launch_bounds__(256) void k_aggxg(const float4* __restrict__ x,
                                               const int* __restrict__ rowptr,
                                               const unsigned* __restrict__ edges,
                                               const float* __restrict__ dinv,
                                               const float* __restrict__ W1, const float* __restrict__ b1,
                                               unsigned* __restrict__ hA /* fp8 rows, as u32 */) {
    __shared__ float4 sx[256];
    __shared__ float sW[4 * HID];
    __shared__ float sb[HID];
    int tid = threadIdx.x;
    sW[tid] = W1[tid];
    sW[tid + 256] = W1[tid + 256];
    if (tid < HID) sb[tid] = b1[tid];

    int i = blockIdx.x * 256 + tid;
    float4 agg = make_float4(0.f, 0.f, 0.f, 0.f);
    if (i < N_NODES) {
        float di = dinv[i];
        float4 xv = x[i];
        float c0 = di * di;
        agg.x = c0 * xv.x; agg.y = c0 * xv.y; agg.z = c0 * xv.z; agg.w = c0 * xv.w;
        int beg = rowptr[i], end = rowptr[i + 1];
        for (int e = beg; e < end; ++e) {
            unsigned r = edges[e];
            float c = rec_coef(r);
            float4 v = x[r >> 15];
            agg.x = fmaf(c, v.x, agg.x); agg.y = fmaf(c, v.y, agg.y);
            agg.z = fmaf(c, v.z, agg.z); agg.w = fmaf(c, v.w, agg.w);
        }
    }
    sx[tid] = agg;
    __syncthreads();

    int node0 = blockIdx.x * 256;
#pragma unroll
    for (int it = 0; it < 32; ++it) {
        int id = it * 256 + tid;
        int n = id >> 5;          // local node 0..255
        int g = id & 31;          // column group (4 cols)
        int node = node0 + n;
        if (node >= N_NODES) continue;
        float4 a = sx[n];
        float c[4];
#pragma unroll
        for (int j = 0; j < 4; ++j) {
            int col = g * 4 + j;
            float v = sb[col];
            v = fmaf(a.x, sW[col],           v);
            v = fmaf(a.y, sW[HID + col],     v);
            v = fmaf(a.z, sW[2 * HID + col], v);
            v = fmaf(a.w, sW[3 * HID + col], v);
            c[j] = fmaxf(v, 0.0f);
        }
        unsigned lo = __hip_fp8x2_e4m3(make_float2(c[0], c[1])).__x;
        unsigned hi = __hip_fp8x2_e4m3(make_float2(c[2], c[3])).__x;
        hA[node * 32 + g] = lo | (hi << 16);
    }
}

// ---------------- CSR aggregation, fp8 payload: one wave per node, fp8x2 per lane ------------
__global__ __launch_bounds__(256) void k_agg8(const unsigned short* __restrict__ h8,
                                              const int* __restrict__ rowptr,
                                              const unsigned* __restrict__ edges,
                                              const float* __restrict__ dinv,
                                              f16x2* __restrict__ out) {
    int node = blockIdx.x * 4 + (threadIdx.x >> 6);
    if (node >= N_NODES) return;
    int lane = threadIdx.x & 63;
    int beg = rowptr[node], end = rowptr[node + 1];
    float di = dinv[node];
    float2 self = fp8x2_to_f32x2(h8[node * 64 + lane]);
    float c0 = di * di;
    float accx = c0 * self.x;
    float accy = c0 * self.y;
    int e = beg;
    for (; e + 8 <= end; e += 8) {
        unsigned r0 = edges[e + 0], r1 = edges[e + 1], r2 = edges[e + 2], r3 = edges[e + 3];
        unsigned r4 = edges[e + 4], r5 = edges[e + 5], r6 = edges[e + 6], r7 = edges[e + 7];
        unsigned short w0 = h8[(r0 >> 15) * 64 + lane], w1 = h8[(r1 >> 15) * 64 + lane];
        unsigned short w2 = h8[(r2 >> 15) * 64 + lane], w3 = h8[(r3 >> 15) * 64 + lane];
        unsigned short w4 = h8[(r4 >> 15) * 64 + lane], w5 = h8[(r5 >> 15) * 64 + lane];
        unsigned short w6 = h8[(r6 >> 15) * 64 + lane], w7 = h8[(r7 >> 15) * 64 + lane];
        float2 v0 = fp8x2_to_f32x2(w0), v1 = fp8x2_to_f32x2(w1);
        float2 v2 = fp8x2_to_f32x2(w2), v3 = fp8x2_to_f32x2(w3);
        float2 v4 = fp8x2_to_f32x2(w4), v5 = fp8x2_to_f32x2(w5);
        float2 v6 = fp8x2_to_f32x2(w6), v7 = fp8x2_to_f32x2(w7);
        float c0f = rec_coef(r0), c1f = rec_coef(r1), c2f = rec_coef(r2), c3f = rec_coef(r3);
        float c4f = rec_coef(r4), c5f = rec_coef(r5), c6f = rec_coef(r6), c7f = rec_coef(r7);
        accx = fmaf(c0f, v0.x, accx); accy = fmaf(c0f, v0.y, accy);
        accx = fmaf(c1f, v1.x, accx); accy = fmaf(c1f, v1.y, accy);
        accx = fmaf(c2f, v2.x, accx); accy = fmaf(c2f, v2.y, accy);
        accx = fmaf(c3f, v3.x, accx); accy = fmaf(c3f, v3.y, accy);
        accx = fmaf(c4f, v4.x, accx); accy = fmaf(c4f, v4.y, accy);
        accx = fmaf(c5f, v5.x, accx); accy = fmaf(c5f, v5.y, accy);
        accx = fmaf(c6f, v6.x, accx); accy = fmaf(c6f, v6.y, accy);
        accx = fmaf(c7f, v7.x, accx); accy = fmaf(c7f, v7.y, accy);
    }
    for (; e < end; ++e) {
        unsigned r = edges[e];
        float2 v = fp8x2_to_f32x2(h8[(r >> 15) * 64 + lane]);
        float c = rec_coef(r);
        accx = fmaf(c, v.x, accx);
        accy = fmaf(c, v.y, accy);
    }
    f16x2 o;
    o.x = (f16)accx;
    o.y = (f16)accy;
    out[node * 64 + lane] = o;
}

// ---------------- pack 3x W (128x128 fp32) into MFMA B-fragment order, fp16, one launch -----
__global__ __launch_bounds__(256) void k_packW3(const float* __restrict__ W2, const float* __restrict__ W3,
                                                const float* __restrict__ W4, f16* __restrict__ Wp) {
    int idx = blockIdx.x * 256 + threadIdx.x;   // 192 blocks x 256 = 49152 = 3 * 16384
    int which = idx >> 14;
    int r = idx & 16383;
    const float* W = (which == 0) ? W2 : (which == 1) ? W3 : W4;
    int j  = r & 7;
    int L  = (r >> 3) & 63;
    int ks = (r >> 9) & 3;
    int ct = r >> 11;
    int k = ks * 32 + (L >> 4) * 8 + j;
    int n = ct * 16 + (L & 15);
    Wp[idx] = (f16)W[k * HID + n];
}

// ---------------- main GEMM via MFMA: (N x 128 f16) @ Wp + bias, ReLU; fp8 or fp16 out -------
template <bool FP8OUT>
__global__ __launch_bounds__(256) void k_gemm_mfma(const f16* __restrict__ A, const f16* __restrict__ Wp,
                                                   const float* __restrict__ bias, void* __restrict__ outv) {
    int wave = threadIdx.x >> 6;
    int lane = threadIdx.x & 63;
    int row0 = blockIdx.x * 64 + wave * 16;
    if (row0 >= N_NODES) return;
    int m = lane & 15;
    int q = lane >> 4;
    const f16* Arow = A + (size_t)(row0 + m) * HID + q * 8;

    f32x4 acc[8];
#pragma unroll
    for (int t = 0; t < 8; ++t) acc[t] = (f32x4){0.f, 0.f, 0.f, 0.f};

#pragma unroll
    for (int ks = 0; ks < 4; ++ks) {
        f16x8 a = *(const f16x8*)(Arow + ks * 32);
#pragma unroll
        for (int t = 0; t < 8; ++t) {
            f16x8 b = *(const f16x8*)(Wp + ((size_t)(t * 4 + ks) * 64 + lane) * 8);
            acc[t] = __builtin_amdgcn_mfma_f32_16x16x32_f16(a, b, acc[t], 0, 0, 0);
        }
    }

    int orow = row0 + q * 4;
#pragma unroll
    for (int t = 0; t < 8; ++t) {
        float bb = bias[t * 16 + m];
#pragma unroll
        for (int r = 0; r < 4; ++r) {
            float val = fmaxf(acc[t][r] + bb, 0.0f);
            if constexpr (FP8OUT) {
                __hip_fp8_e4m3* out8 = (__hip_fp8_e4m3*)outv;
                out8[(size_t)(orow + r) * HID + t * 16 + m] = __hip_fp8_e4m3(val);
            } else {
                f16* out = (f16*)outv;
                out[(size_t)(orow + r) * HID + t * 16 + m] = (f16)val;
            }
        }
    }
}

// ---------------- pooling pass 1: per (graph, segment) partial sums, fp32, deterministic -----
__device__ __forceinline__ int lower_bound_batch(const int* __restrict__ batch, int val) {
    int lo = 0, hi = N_NODES;
    while (lo < hi) { int m = (lo + hi) >> 1; if (batch[m] < val) lo = m + 1; else hi = m; }
    return lo;
}

__global__ __launch_bounds__(128) void k_pool1(const f16* __restrict__ h, const int* __restrict__ batch,
                                               float* __restrict__ partials) {
    int g = blockIdx.x / POOL_SEG;
    int s = blockIdx.x % POOL_SEG;
    int f = threadIdx.x;
    int beg = lower_bound_batch(batch, g);
    int end = lower_bound_batch(batch, g + 1);
    int len = end - beg;
    int sb = beg + (int)(((long long)len * s) / POOL_SEG);
    int se = beg + (int)(((long long)len * (s + 1)) / POOL_SEG);
    float acc = 0.0f;
    for (int i = sb; i < se; ++i) acc += (float)h[i * HID + f];
    partials[(size_t)blockIdx.x * HID + f] = acc;
}

// ---------------- pooling pass 2 + head fused ---------------
__global__ __launch_bounds__(128) void k_pool2h(const float* __restrict__ partials,
                                                const int* __restrict__ batch,
                                                const float* __restrict__ Wl, const float* __restrict__ bl,
                                                float* __restrict__ out) {
    __shared__ float sp[HID];
    int g = blockIdx.x;
    int f = threadIdx.x;
    float acc = 0.0f;
#pragma unroll
    for (int s = 0; s < POOL_SEG; ++s)
        acc += partials[(size_t)(g * POOL_SEG + s) * HID + f];
    int beg = lower_bound_batch(batch, g);
    int end = lower_bound_batch(batch, g + 1);
    sp[f] = acc / fmaxf((float)(end - beg), 1.0f);
    __syncthreads();
    if (f < N_CLS) {
        float v = bl[f];
        for (int k = 0; k < HID; ++k) v = fmaf(sp[k], Wl[k * N_CLS + f], v);
        out[g * N_CLS + f] = 1.0f / (1.0f + expf(-v));
    }
}

extern "C" void kernel_launch(void* const* d_in, const int* in_sizes, int n_in,
                              void* d_out, int out_size, void* d_ws, size_t ws_size,
                              hipStream_t stream) {
    const float* x     = (const float*)d_in[0];
    const int*   ei    = (const int*)d_in[1];
    const int*   batch = (const int*)d_in[2];
    const float* W1 = (const float*)d_in[3];  const float* b1 = (const float*)d_in[4];
    const float* W2 = (const float*)d_in[5];  const float* b2 = (const float*)d_in[6];
    const float* W3 = (const float*)d_in[7];  const float* b3 = (const float*)d_in[8];
    const float* W4 = (const float*)d_in[9];  const float* b4 = (const float*)d_in[10];
    const float* Wl = (const float*)d_in[11]; const float* bl = (const float*)d_in[12];
    float* out = (float*)d_out;

    char* p = (char*)d_ws;
    auto alloc = [&](size_t bytes) { char* r = p; p += (bytes + 255) & ~(size_t)255; return (void*)r; };
    int*      C      = (int*)     alloc((size_t)NCHUNK * NBUK * 4);
    int*      Off    = (int*)     alloc((size_t)NCHUNK * NBUK * 4);
    int*      bbase  = (int*)     alloc((size_t)(NBUK + 1) * 4);
    unsigned* bkt    = (unsigned*)alloc((size_t)N_EDGES * 4);
    int*      csrSrc = (int*)     alloc((size_t)N_EDGES * 4);
    int*      rowptr = (int*)     alloc((size_t)(N_NODES + 1) * 4);
    float*    dinv   = (float*)   alloc((size_t)N_NODES * 4);
    unsigned* edges  = (unsigned*)alloc((size_t)N_EDGES * 4);
    unsigned* hA     = (unsigned*)alloc((size_t)N_NODES * HID);      // fp8 gather source
    f16*      hB     = (f16*)     alloc((size_t)N_NODES * HID * 2);  // fp16 agg out / GEMM A
    f16*      h4     = (f16*)     alloc((size_t)N_NODES * HID * 2);  // fp16 final layer out
    float*    parts  = (float*)   alloc((size_t)N_GRAPH * POOL_SEG * HID * 4);
    f16*      Wp     = (f16*)     alloc((size_t)3 * HID * HID * 2);
    f16*      Wp2 = Wp;
    f16*      Wp3 = Wp + HID * HID;
    f16*      Wp4 = Wp + 2 * HID * HID;

    const int* srcv = ei;              // edge_index[0]
    const int* dstv = ei + N_EDGES;    // edge_index[1]

    const int nb = (N_NODES + 255) / 256;   // 391

    // CSR build: bucketed, no global atomics
    k_bc     <<<NCHUNK, 256, 0, stream>>>(dstv, C);
    k_bscan  <<<1, 256, 0, stream>>>(C, Off, bbase, rowptr);
    k_scatter<<<NCHUNK, 256, 0, stream>>>(srcv, dstv, Off, bbase, bkt);
    k_local  <<<NBUK, 256, 0, stream>>>(bkt, bbase, rowptr, dinv, csrSrc);
    k_coef   <<<nb, 256, 0, stream>>>(csrSrc, rowptr, dinv, edges);

    k_packW3<<<192, 256, 0, stream>>>(W2, W3, W4, Wp);

    // layer 1: fused Agg(x) + (Nx4)@(4x128) GEMM, fp8 out
    k_aggxg<<<nb, 256, 0, stream>>>((const float4*)x, rowptr, edges, dinv, W1, b1, hA);

    // layers 2..4: Agg (fp8 gather, wave-per-node) then MFMA GEMM (+bias, ReLU)
    const int ggrid = (N_NODES + 63) / 64;   // 1563
    k_agg8<<<N_NODES / 4, 256, 0, stream>>>((const unsigned short*)hA, rowptr, edges, dinv, (f16x2*)hB);
    k_gemm_mfma<true ><<<ggrid, 256, 0, stream>>>(hB, Wp2, b2, hA);
    k_agg8<<<N_NODES / 4, 256, 0, stream>>>((const unsigned short*)hA, rowptr, edges, dinv, (f16x2*)hB);
    k_gemm_mfma<true ><<<ggrid, 256, 0, stream>>>(hB, Wp3, b3, hA);
    k_agg8<<<N_NODES / 4, 256, 0, stream>>>((const unsigned short*)hA, rowptr, edges, dinv, (f16x2*)hB);
    k_gemm_mfma<false><<<ggrid, 256, 0, stream>>>(hB, Wp4, b4, h4);

    k_pool1 <<<N_GRAPH * POOL_SEG, 128, 0, stream>>>(h4, batch, parts);
    k_pool2h<<<N_GRAPH, 128, 0, stream>>>(parts, batch, Wl, bl, out);
}

// Round 9
// 405.815 us; speedup vs baseline: 1.5664x; 1.1063x over previous
//
#include <hip/hip_runtime.h>
#include <hip/hip_fp8.h>
#include <math.h>

#define N_NODES 100000
#define N_EDGES 1600000
#define F_IN    4
#define HID     128
#define N_CLS   5
#define N_GRAPH 256
#define POOL_SEG 8

#define BSHIFT   9
#define BSIZE    512
#define NBUK     196            // ceil(100000 / 512)
#define NCHUNK   200
#define CHUNK    8000           // 200 * 8000 = 1.6M exactly

typedef _Float16 f16;
typedef _Float16 f16x2 __attribute__((ext_vector_type(2)));
typedef _Float16 f16x8 __attribute__((ext_vector_type(8)));
typedef float f32x4 __attribute__((ext_vector_type(4)));

// decode 4-byte edge record: [src:17 | coef-f16-positive:15]
__device__ __forceinline__ float rec_coef(unsigned r) {
    return (float)__builtin_bit_cast(_Float16, (unsigned short)(r & 0x7FFFu));
}

__device__ __forceinline__ float2 fp8x2_to_f32x2(unsigned short raw) {
    __hip_fp8x2_e4m3 t;
    t.__x = raw;
    return static_cast<float2>(t);
}

// 8 fp8 values (uint2) -> fma into acc[0..7] with coefficient c
__device__ __forceinline__ void fma8(float c, uint2 v, float* acc) {
    float2 p0 = fp8x2_to_f32x2((unsigned short)(v.x & 0xFFFFu));
    float2 p1 = fp8x2_to_f32x2((unsigned short)(v.x >> 16));
    float2 p2 = fp8x2_to_f32x2((unsigned short)(v.y & 0xFFFFu));
    float2 p3 = fp8x2_to_f32x2((unsigned short)(v.y >> 16));
    acc[0] = fmaf(c, p0.x, acc[0]); acc[1] = fmaf(c, p0.y, acc[1]);
    acc[2] = fmaf(c, p1.x, acc[2]); acc[3] = fmaf(c, p1.y, acc[3]);
    acc[4] = fmaf(c, p2.x, acc[4]); acc[5] = fmaf(c, p2.y, acc[5]);
    acc[6] = fmaf(c, p3.x, acc[6]); acc[7] = fmaf(c, p3.y, acc[7]);
}

// ---------------- CSR build step 1: per-(chunk,bucket) counts via LDS histogram -------------
__global__ __launch_bounds__(256) void k_bc(const int* __restrict__ dst, int* __restrict__ C) {
    __shared__ int cnt[NBUK];
    int t = threadIdx.x;
    if (t < NBUK) cnt[t] = 0;
    __syncthreads();
    int base = blockIdx.x * CHUNK;
#pragma unroll
    for (int it = 0; it < 32; ++it) {
        int idx = it * 256 + t;
        if (idx < CHUNK) atomicAdd(&cnt[dst[base + idx] >> BSHIFT], 1);
    }
    __syncthreads();
    if (t < NBUK) C[blockIdx.x * NBUK + t] = cnt[t];
}

// ---------------- step 2: offsets. Off[c][b] = prefix over chunks; bbase = bucket bases -----
__global__ __launch_bounds__(256) void k_bscan(const int* __restrict__ C, int* __restrict__ Off,
                                               int* __restrict__ bbase, int* __restrict__ rowptr) {
    __shared__ int s[256];
    int b = threadIdx.x;
    int tot = 0;
    if (b < NBUK) {
        for (int c = 0; c < NCHUNK; ++c) {
            Off[c * NBUK + b] = tot;
            tot += C[c * NBUK + b];
        }
    }
    s[b] = (b < NBUK) ? tot : 0;
    __syncthreads();
    for (int off = 1; off < 256; off <<= 1) {
        int v = (b >= off) ? s[b - off] : 0;
        __syncthreads();
        s[b] += v;
        __syncthreads();
    }
    if (b < NBUK) bbase[b] = s[b] - tot;   // exclusive
    if (b == 0) { bbase[NBUK] = N_EDGES; rowptr[N_NODES] = N_EDGES; }
}

// ---------------- step 3: scatter packed records into bucket-grouped array ------------------
// record: (src:17)<<9 | (dst & 511)
__global__ __launch_bounds__(256) void k_scatter(const int* __restrict__ src, const int* __restrict__ dst,
                                                 const int* __restrict__ Off, const int* __restrict__ bbase,
                                                 unsigned* __restrict__ bkt) {
    __shared__ int cur[NBUK];
    int t = threadIdx.x;
    if (t < NBUK) cur[t] = bbase[t] + Off[blockIdx.x * NBUK + t];
    __syncthreads();
    int base = blockIdx.x * CHUNK;
#pragma unroll
    for (int it = 0; it < 32; ++it) {
        int idx = it * 256 + t;
        if (idx < CHUNK) {
            int s = src[base + idx], d = dst[base + idx];
            int b = d >> BSHIFT;
            int p = atomicAdd(&cur[b], 1);
            bkt[p] = ((unsigned)s << BSHIFT) | (unsigned)(d & (BSIZE - 1));
        }
    }
}

// ---------------- step 4: per-bucket local CSR (hist -> scan -> scatter), rowptr + dinv -----
__global__ __launch_bounds__(256) void k_local(const unsigned* __restrict__ bkt,
                                               const int* __restrict__ bbase,
                                               int* __restrict__ rowptr, float* __restrict__ dinv,
                                               int* __restrict__ csrSrc) {
    __shared__ int hist[BSIZE], sc[BSIZE], cur[BSIZE];
    int t = threadIdx.x;
    int b = blockIdx.x;
    int s0 = bbase[b], s1 = bbase[b + 1];
    hist[t] = 0; hist[t + 256] = 0;
    __syncthreads();
    for (int e = s0 + t; e < s1; e += 256) atomicAdd(&hist[bkt[e] & (BSIZE - 1)], 1);
    __syncthreads();
    sc[t] = hist[t]; sc[t + 256] = hist[t + 256];
    __syncthreads();
    for (int off = 1; off < BSIZE; off <<= 1) {
        int i0 = t, i1 = t + 256;
        int v0 = (i0 >= off) ? sc[i0 - off] : 0;
        int v1 = (i1 >= off) ? sc[i1 - off] : 0;
        __syncthreads();
        sc[i0] += v0; sc[i1] += v1;
        __syncthreads();
    }
#pragma unroll
    for (int h = 0; h < 2; ++h) {
        int l = t + h * 256;
        int excl = sc[l] - hist[l];
        int node = b * BSIZE + l;
        if (node < N_NODES) {
            rowptr[node] = s0 + excl;
            dinv[node] = rsqrtf((float)hist[l] + 1.0f);
        }
        cur[l] = s0 + excl;
    }
    __syncthreads();
    for (int e = s0 + t; e < s1; e += 256) {
        unsigned r = bkt[e];
        int d = r & (BSIZE - 1);
        int p = atomicAdd(&cur[d], 1);
        csrSrc[p] = (int)(r >> BSHIFT);
    }
}

// ---------------- step 5: attach coefficients, emit final edge records ----------------------
__global__ __launch_bounds__(256) void k_coef(const int* __restrict__ csrSrc,
                                              const int* __restrict__ rowptr,
                                              const float* __restrict__ dinv,
                                              unsigned* __restrict__ edges) {
    int i = blockIdx.x * 256 + threadIdx.x;
    if (i >= N_NODES) return;
    float di = dinv[i];
    int beg = rowptr[i], end = rowptr[i + 1];
    for (int e = beg; e < end; ++e) {
        int s = csrSrc[e];
        float c = di * dinv[s];
        unsigned short cb = __builtin_bit_cast(unsigned short, (f16)c);
        edges[e] = ((unsigned)s << 15) | (unsigned)(cb & 0x7FFFu);
    }
}

// ---------------- FUSED layer 1: Agg(x) (thread-per-node) + (Nx4)@(4x128) GEMM, fp8 out -----
__global__ __launch_bounds__(256) void k_aggxg(const float4* __restrict__ x,
                                               const int* __restrict__ rowptr,
                                               const unsigned* __restrict__ edges,
                                               const float* __restrict__ dinv,
                                               const float* __restrict__ W1, const float* __restrict__ b1,
                                               unsigned* __restrict__ hA /* fp8 rows, as u32 */) {
    __shared__ float4 sx[256];
    __shared__ float sW[4 * HID];
    __shared__ float sb[HID];
    int tid = threadIdx.x;
    sW[tid] = W1[tid];
    sW[tid + 256] = W1[tid + 256];
    if (tid < HID) sb[tid] = b1[tid];

    int i = blockIdx.x * 256 + tid;
    float4 agg = make_float4(0.f, 0.f, 0.f, 0.f);
    if (i < N_NODES) {
        float di = dinv[i];
        float4 xv = x[i];
        float c0 = di * di;
        agg.x = c0 * xv.x; agg.y = c0 * xv.y; agg.z = c0 * xv.z; agg.w = c0 * xv.w;
        int beg = rowptr[i], end = rowptr[i + 1];
        for (int e = beg; e < end; ++e) {
            unsigned r = edges[e];
            float c = rec_coef(r);
            float4 v = x[r >> 15];
            agg.x = fmaf(c, v.x, agg.x); agg.y = fmaf(c, v.y, agg.y);
            agg.z = fmaf(c, v.z, agg.z); agg.w = fmaf(c, v.w, agg.w);
        }
    }
    sx[tid] = agg;
    __syncthreads();

    int node0 = blockIdx.x * 256;
#pragma unroll
    for (int it = 0; it < 32; ++it) {
        int id = it * 256 + tid;
        int n = id >> 5;          // local node 0..255
        int g = id & 31;          // column group (4 cols)
        int node = node0 + n;
        if (node >= N_NODES) continue;
        float4 a = sx[n];
        float c[4];
#pragma unroll
        for (int j = 0; j < 4; ++j) {
            int col = g * 4 + j;
            float v = sb[col];
            v = fmaf(a.x, sW[col],           v);
            v = fmaf(a.y, sW[HID + col],     v);
            v = fmaf(a.z, sW[2 * HID + col], v);
            v = fmaf(a.w, sW[3 * HID + col], v);
            c[j] = fmaxf(v, 0.0f);
        }
        unsigned lo = __hip_fp8x2_e4m3(make_float2(c[0], c[1])).__x;
        unsigned hi = __hip_fp8x2_e4m3(make_float2(c[2], c[3])).__x;
        hA[node * 32 + g] = lo | (hi << 16);
    }
}

// ---------------- CSR aggregation, fp8 payload, 4 rows per VMEM instruction ------------------
// Wave = 4 groups x 16 lanes. Group g handles edge slot g; sublane l covers features 8l..8l+7
// (uint2 = 8 fp8 per lane; 16 lanes x 8 B = full 128-B row in ONE instruction per group —
//  i.e. one wave instruction gathers 4 rows). Edge records for 16 edges come from one
//  coalesced dword load, distributed via __shfl (VALU pipe is underused).
__global__ __launch_bounds__(256) void k_agg8w(const unsigned* __restrict__ h8,
                                               const int* __restrict__ rowptr,
                                               const unsigned* __restrict__ edges,
                                               const float* __restrict__ dinv,
                                               f16* __restrict__ out) {
    int node = blockIdx.x * 4 + (threadIdx.x >> 6);
    if (node >= N_NODES) return;
    int lane = threadIdx.x & 63;
    int g = lane >> 4;          // edge slot 0..3
    int l = lane & 15;          // sublane: features 8l..8l+7
    int beg = rowptr[node], end = rowptr[node + 1];

    float acc[8];
    // self contribution (group 0 carries it; groups 1-3 add zero)
    {
        float di = dinv[node];
        float c0 = (g == 0) ? di * di : 0.0f;
        uint2 v = *(const uint2*)(h8 + (size_t)node * 32 + l * 2);
        float2 p0 = fp8x2_to_f32x2((unsigned short)(v.x & 0xFFFFu));
        float2 p1 = fp8x2_to_f32x2((unsigned short)(v.x >> 16));
        float2 p2 = fp8x2_to_f32x2((unsigned short)(v.y & 0xFFFFu));
        float2 p3 = fp8x2_to_f32x2((unsigned short)(v.y >> 16));
        acc[0] = c0 * p0.x; acc[1] = c0 * p0.y;
        acc[2] = c0 * p1.x; acc[3] = c0 * p1.y;
        acc[4] = c0 * p2.x; acc[5] = c0 * p2.y;
        acc[6] = c0 * p3.x; acc[7] = c0 * p3.y;
    }

    int e = beg;
    // main loop: 16 edges per outer iteration, 1 record-load + 4 row-gather instructions
    for (; e + 16 <= end; e += 16) {
        unsigned rec16 = edges[e + l];     // lanes 0-15 hold records e..e+15 (groups replicate)
#pragma unroll
        for (int i = 0; i < 4; ++i) {
            unsigned rec = __shfl(rec16, i * 4 + g, 64);
            float c = rec_coef(rec);
            uint2 v = *(const uint2*)(h8 + (size_t)(rec >> 15) * 32 + l * 2);
            fma8(c, v, acc);
        }
    }
    // tail: up to 4 edges per step, lanes beyond the remainder masked to zero coef
    for (; e < end; e += 4) {
        int rem = end - e;
        int idx = (g < rem) ? g : rem - 1;
        unsigned rec = edges[e + idx];
        float c = (g < rem) ? rec_coef(rec) : 0.0f;
        uint2 v = *(const uint2*)(h8 + (size_t)(rec >> 15) * 32 + l * 2);
        fma8(c, v, acc);
    }

    // sum the 4 group-partials
#pragma unroll
    for (int j = 0; j < 8; ++j) {
        acc[j] += __shfl_xor(acc[j], 16, 64);
        acc[j] += __shfl_xor(acc[j], 32, 64);
    }
    if (lane < 16) {
        f16x8 o;
#pragma unroll
        for (int j = 0; j < 8; ++j) o[j] = (f16)acc[j];
        *(f16x8*)(out + (size_t)node * HID + l * 8) = o;
    }
}

// ---------------- pack 3x W (128x128 fp32) into MFMA B-fragment order, fp16, one launch -----
__global__ __launch_bounds__(256) void k_packW3(const float* __restrict__ W2, const float* __restrict__ W3,
                                                const float* __restrict__ W4, f16* __restrict__ Wp) {
    int idx = blockIdx.x * 256 + threadIdx.x;   // 192 blocks x 256 = 49152 = 3 * 16384
    int which = idx >> 14;
    int r = idx & 16383;
    const float* W = (which == 0) ? W2 : (which == 1) ? W3 : W4;
    int j  = r & 7;
    int L  = (r >> 3) & 63;
    int ks = (r >> 9) & 3;
    int ct = r >> 11;
    int k = ks * 32 + (L >> 4) * 8 + j;
    int n = ct * 16 + (L & 15);
    Wp[idx] = (f16)W[k * HID + n];
}

// ---------------- main GEMM via MFMA: (N x 128 f16) @ Wp + bias, ReLU; fp8 or fp16 out -------
template <bool FP8OUT>
__global__ __launch_bounds__(256) void k_gemm_mfma(const f16* __restrict__ A, const f16* __restrict__ Wp,
                                                   const float* __restrict__ bias, void* __restrict__ outv) {
    int wave = threadIdx.x >> 6;
    int lane = threadIdx.x & 63;
    int row0 = blockIdx.x * 64 + wave * 16;
    if (row0 >= N_NODES) return;
    int m = lane & 15;
    int q = lane >> 4;
    const f16* Arow = A + (size_t)(row0 + m) * HID + q * 8;

    f32x4 acc[8];
#pragma unroll
    for (int t = 0; t < 8; ++t) acc[t] = (f32x4){0.f, 0.f, 0.f, 0.f};

#pragma unroll
    for (int ks = 0; ks < 4; ++ks) {
        f16x8 a = *(const f16x8*)(Arow + ks * 32);
#pragma unroll
        for (int t = 0; t < 8; ++t) {
            f16x8 b = *(const f16x8*)(Wp + ((size_t)(t * 4 + ks) * 64 + lane) * 8);
            acc[t] = __builtin_amdgcn_mfma_f32_16x16x32_f16(a, b, acc[t], 0, 0, 0);
        }
    }

    int orow = row0 + q * 4;
#pragma unroll
    for (int t = 0; t < 8; ++t) {
        float bb = bias[t * 16 + m];
#pragma unroll
        for (int r = 0; r < 4; ++r) {
            float val = fmaxf(acc[t][r] + bb, 0.0f);
            if constexpr (FP8OUT) {
                __hip_fp8_e4m3* out8 = (__hip_fp8_e4m3*)outv;
                out8[(size_t)(orow + r) * HID + t * 16 + m] = __hip_fp8_e4m3(val);
            } else {
                f16* out = (f16*)outv;
                out[(size_t)(orow + r) * HID + t * 16 + m] = (f16)val;
            }
        }
    }
}

// ---------------- pooling pass 1: per (graph, segment) partial sums, fp32, deterministic -----
__device__ __forceinline__ int lower_bound_batch(const int* __restrict__ batch, int val) {
    int lo = 0, hi = N_NODES;
    while (lo < hi) { int m = (lo + hi) >> 1; if (batch[m] < val) lo = m + 1; else hi = m; }
    return lo;
}

__global__ __launch_bounds__(128) void k_pool1(const f16* __restrict__ h, const int* __restrict__ batch,
                                               float* __restrict__ partials) {
    int g = blockIdx.x / POOL_SEG;
    int s = blockIdx.x % POOL_SEG;
    int f = threadIdx.x;
    int beg = lower_bound_batch(batch, g);
    int end = lower_bound_batch(batch, g + 1);
    int len = end - beg;
    int sb = beg + (int)(((long long)len * s) / POOL_SEG);
    int se = beg + (int)(((long long)len * (s + 1)) / POOL_SEG);
    float acc = 0.0f;
    for (int i = sb; i < se; ++i) acc += (float)h[i * HID + f];
    partials[(size_t)blockIdx.x * HID + f] = acc;
}

// ---------------- pooling pass 2 + head fused ---------------
__global__ __launch_bounds__(128) void k_pool2h(const float* __restrict__ partials,
                                                const int* __restrict__ batch,
                                                const float* __restrict__ Wl, const float* __restrict__ bl,
                                                float* __restrict__ out) {
    __shared__ float sp[HID];
    int g = blockIdx.x;
    int f = threadIdx.x;
    float acc = 0.0f;
#pragma unroll
    for (int s = 0; s < POOL_SEG; ++s)
        acc += partials[(size_t)(g * POOL_SEG + s) * HID + f];
    int beg = lower_bound_batch(batch, g);
    int end = lower_bound_batch(batch, g + 1);
    sp[f] = acc / fmaxf((float)(end - beg), 1.0f);
    __syncthreads();
    if (f < N_CLS) {
        float v = bl[f];
        for (int k = 0; k < HID; ++k) v = fmaf(sp[k], Wl[k * N_CLS + f], v);
        out[g * N_CLS + f] = 1.0f / (1.0f + expf(-v));
    }
}

extern "C" void kernel_launch(void* const* d_in, const int* in_sizes, int n_in,
                              void* d_out, int out_size, void* d_ws, size_t ws_size,
                              hipStream_t stream) {
    const float* x     = (const float*)d_in[0];
    const int*   ei    = (const int*)d_in[1];
    const int*   batch = (const int*)d_in[2];
    const float* W1 = (const float*)d_in[3];  const float* b1 = (const float*)d_in[4];
    const float* W2 = (const float*)d_in[5];  const float* b2 = (const float*)d_in[6];
    const float* W3 = (const float*)d_in[7];  const float* b3 = (const float*)d_in[8];
    const float* W4 = (const float*)d_in[9];  const float* b4 = (const float*)d_in[10];
    const float* Wl = (const float*)d_in[11]; const float* bl = (const float*)d_in[12];
    float* out = (float*)d_out;

    char* p = (char*)d_ws;
    auto alloc = [&](size_t bytes) { char* r = p; p += (bytes + 255) & ~(size_t)255; return (void*)r; };
    int*      C      = (int*)     alloc((size_t)NCHUNK * NBUK * 4);
    int*      Off    = (int*)     alloc((size_t)NCHUNK * NBUK * 4);
    int*      bbase  = (int*)     alloc((size_t)(NBUK + 1) * 4);
    unsigned* bkt    = (unsigned*)alloc((size_t)N_EDGES * 4);
    int*      csrSrc = (int*)     alloc((size_t)N_EDGES * 4);
    int*      rowptr = (int*)     alloc((size_t)(N_NODES + 1) * 4);
    float*    dinv   = (float*)   alloc((size_t)N_NODES * 4);
    unsigned* edges  = (unsigned*)alloc((size_t)N_EDGES * 4);
    unsigned* hA     = (unsigned*)alloc((size_t)N_NODES * HID);      // fp8 gather source
    f16*      hB     = (f16*)     alloc((size_t)N_NODES * HID * 2);  // fp16 agg out / GEMM A
    f16*      h4     = (f16*)     alloc((size_t)N_NODES * HID * 2);  // fp16 final layer out
    float*    parts  = (float*)   alloc((size_t)N_GRAPH * POOL_SEG * HID * 4);
    f16*      Wp     = (f16*)     alloc((size_t)3 * HID * HID * 2);
    f16*      Wp2 = Wp;
    f16*      Wp3 = Wp + HID * HID;
    f16*      Wp4 = Wp + 2 * HID * HID;

    const int* srcv = ei;              // edge_index[0]
    const int* dstv = ei + N_EDGES;    // edge_index[1]

    const int nb = (N_NODES + 255) / 256;   // 391

    // CSR build: bucketed, no global atomics
    k_bc     <<<NCHUNK, 256, 0, stream>>>(dstv, C);
    k_bscan  <<<1, 256, 0, stream>>>(C, Off, bbase, rowptr);
    k_scatter<<<NCHUNK, 256, 0, stream>>>(srcv, dstv, Off, bbase, bkt);
    k_local  <<<NBUK, 256, 0, stream>>>(bkt, bbase, rowptr, dinv, csrSrc);
    k_coef   <<<nb, 256, 0, stream>>>(csrSrc, rowptr, dinv, edges);

    k_packW3<<<192, 256, 0, stream>>>(W2, W3, W4, Wp);

    // layer 1: fused Agg(x) + (Nx4)@(4x128) GEMM, fp8 out
    k_aggxg<<<nb, 256, 0, stream>>>((const float4*)x, rowptr, edges, dinv, W1, b1, hA);

    // layers 2..4: Agg (fp8 gather, 4 rows/VMEM-inst) then MFMA GEMM (+bias, ReLU)
    const int ggrid = (N_NODES + 63) / 64;   // 1563
    k_agg8w<<<N_NODES / 4, 256, 0, stream>>>(hA, rowptr, edges, dinv, hB);
    k_gemm_mfma<true ><<<ggrid, 256, 0, stream>>>(hB, Wp2, b2, hA);
    k_agg8w<<<N_NODES / 4, 256, 0, stream>>>(hA, rowptr, edges, dinv, hB);
    k_gemm_mfma<true ><<<ggrid, 256, 0, stream>>>(hB, Wp3, b3, hA);
    k_agg8w<<<N_NODES / 4, 256, 0, stream>>>(hA, rowptr, edges, dinv, hB);
    k_gemm_mfma<false><<<ggrid, 256, 0, stream>>>(hB, Wp4, b4, h4);

    k_pool1 <<<N_GRAPH * POOL_SEG, 128, 0, stream>>>(h4, batch, parts);
    k_pool2h<<<N_GRAPH, 128, 0, stream>>>(parts, batch, Wl, bl, out);
}

// Round 10
// 377.013 us; speedup vs baseline: 1.6861x; 1.0764x over previous
//
#include <hip/hip_runtime.h>
#include <hip/hip_fp8.h>
#include <math.h>

#define N_NODES 100000
#define N_EDGES 1600000
#define F_IN    4
#define HID     128
#define N_CLS   5
#define N_GRAPH 256
#define POOL_SEG 8

#define BSHIFT   9
#define BSIZE    512
#define NBUK     196            // ceil(100000 / 512)
#define NCHUNK   200
#define CHUNK    8000           // 200 * 8000 = 1.6M exactly

typedef _Float16 f16;
typedef _Float16 f16x2 __attribute__((ext_vector_type(2)));
typedef _Float16 f16x8 __attribute__((ext_vector_type(8)));
typedef float f32x4 __attribute__((ext_vector_type(4)));

// decode 4-byte edge record: [src:17 | coef-f16-positive:15]; record 0 == dummy (src 0, coef 0)
__device__ __forceinline__ float rec_coef(unsigned r) {
    return (float)__builtin_bit_cast(_Float16, (unsigned short)(r & 0x7FFFu));
}

__device__ __forceinline__ float2 fp8x2_to_f32x2(unsigned short raw) {
    __hip_fp8x2_e4m3 t;
    t.__x = raw;
    return static_cast<float2>(t);
}

// 8 fp8 values (uint2) -> fma into acc[0..7] with coefficient c
__device__ __forceinline__ void fma8(float c, uint2 v, float* acc) {
    float2 p0 = fp8x2_to_f32x2((unsigned short)(v.x & 0xFFFFu));
    float2 p1 = fp8x2_to_f32x2((unsigned short)(v.x >> 16));
    float2 p2 = fp8x2_to_f32x2((unsigned short)(v.y & 0xFFFFu));
    float2 p3 = fp8x2_to_f32x2((unsigned short)(v.y >> 16));
    acc[0] = fmaf(c, p0.x, acc[0]); acc[1] = fmaf(c, p0.y, acc[1]);
    acc[2] = fmaf(c, p1.x, acc[2]); acc[3] = fmaf(c, p1.y, acc[3]);
    acc[4] = fmaf(c, p2.x, acc[4]); acc[5] = fmaf(c, p2.y, acc[5]);
    acc[6] = fmaf(c, p3.x, acc[6]); acc[7] = fmaf(c, p3.y, acc[7]);
}

// ---------------- CSR build step 1: per-(chunk,bucket) counts via LDS histogram -------------
__global__ __launch_bounds__(256) void k_bc(const int* __restrict__ dst, int* __restrict__ C) {
    __shared__ int cnt[NBUK];
    int t = threadIdx.x;
    if (t < NBUK) cnt[t] = 0;
    __syncthreads();
    int base = blockIdx.x * CHUNK;
#pragma unroll
    for (int it = 0; it < 32; ++it) {
        int idx = it * 256 + t;
        if (idx < CHUNK) atomicAdd(&cnt[dst[base + idx] >> BSHIFT], 1);
    }
    __syncthreads();
    if (t < NBUK) C[blockIdx.x * NBUK + t] = cnt[t];
}

// ---------------- step 2: offsets. Off[c][b] = prefix over chunks; bbase = bucket bases -----
__global__ __launch_bounds__(256) void k_bscan(const int* __restrict__ C, int* __restrict__ Off,
                                               int* __restrict__ bbase) {
    __shared__ int s[256];
    int b = threadIdx.x;
    int tot = 0;
    if (b < NBUK) {
        for (int c = 0; c < NCHUNK; ++c) {
            Off[c * NBUK + b] = tot;
            tot += C[c * NBUK + b];
        }
    }
    s[b] = (b < NBUK) ? tot : 0;
    __syncthreads();
    for (int off = 1; off < 256; off <<= 1) {
        int v = (b >= off) ? s[b - off] : 0;
        __syncthreads();
        s[b] += v;
        __syncthreads();
    }
    if (b < NBUK) bbase[b] = s[b] - tot;   // exclusive
    if (b == 0) bbase[NBUK] = N_EDGES;
}

// ---------------- step 3: scatter packed records into bucket-grouped array ------------------
// record: (src:17)<<9 | (dst & 511)
__global__ __launch_bounds__(256) void k_scatter(const int* __restrict__ src, const int* __restrict__ dst,
                                                 const int* __restrict__ Off, const int* __restrict__ bbase,
                                                 unsigned* __restrict__ bkt) {
    __shared__ int cur[NBUK];
    int t = threadIdx.x;
    if (t < NBUK) cur[t] = bbase[t] + Off[blockIdx.x * NBUK + t];
    __syncthreads();
    int base = blockIdx.x * CHUNK;
#pragma unroll
    for (int it = 0; it < 32; ++it) {
        int idx = it * 256 + t;
        if (idx < CHUNK) {
            int s = src[base + idx], d = dst[base + idx];
            int b = d >> BSHIFT;
            int p = atomicAdd(&cur[b], 1);
            bkt[p] = ((unsigned)s << BSHIFT) | (unsigned)(d & (BSIZE - 1));
        }
    }
}

// ---------------- step 4: per-bucket degree hist -> deg, dinv, padded bucket total ----------
__global__ __launch_bounds__(256) void k_hist2(const unsigned* __restrict__ bkt,
                                               const int* __restrict__ bbase,
                                               int* __restrict__ deg, float* __restrict__ dinv,
                                               int* __restrict__ padTot) {
    __shared__ int hist[BSIZE];
    __shared__ int tot;
    int t = threadIdx.x, b = blockIdx.x;
    hist[t] = 0; hist[t + 256] = 0;
    if (t == 0) tot = 0;
    __syncthreads();
    int s0 = bbase[b], s1 = bbase[b + 1];
    for (int e = s0 + t; e < s1; e += 256) atomicAdd(&hist[bkt[e] & (BSIZE - 1)], 1);
    __syncthreads();
    int loc = 0;
#pragma unroll
    for (int h = 0; h < 2; ++h) {
        int l = t + h * 256;
        int node = b * BSIZE + l;
        int d = hist[l];
        if (node < N_NODES) {
            deg[node] = d;
            dinv[node] = rsqrtf((float)d + 1.0f);
        }
        loc += (d + 15) >> 4;
    }
    atomicAdd(&tot, loc);
    __syncthreads();
    if (t == 0) padTot[b] = tot << 4;
}

// ---------------- step 5: scan padded bucket totals -> padded bases ------------------------
__global__ __launch_bounds__(256) void k_pscan(const int* __restrict__ padTot, int* __restrict__ padBase,
                                               int* __restrict__ rowptrP) {
    __shared__ int s[256];
    int b = threadIdx.x;
    int v = (b < NBUK) ? padTot[b] : 0;
    s[b] = v;
    __syncthreads();
    for (int off = 1; off < 256; off <<= 1) {
        int u = (b >= off) ? s[b - off] : 0;
        __syncthreads();
        s[b] += u;
        __syncthreads();
    }
    if (b < NBUK) padBase[b] = s[b] - v;
    if (b == 0) {
        padBase[NBUK] = s[NBUK - 1];
        rowptrP[N_NODES] = s[NBUK - 1];
    }
}

// ---------------- step 6: per-bucket padded CSR + coef fused; dummy slots = record 0 --------
__global__ __launch_bounds__(256) void k_local2(const unsigned* __restrict__ bkt,
                                                const int* __restrict__ bbase,
                                                const int* __restrict__ deg,
                                                const float* __restrict__ dinv,
                                                const int* __restrict__ padBase,
                                                int* __restrict__ rowptrP,
                                                unsigned* __restrict__ edges) {
    __shared__ int sc[BSIZE];
    __shared__ int cur[BSIZE];
    __shared__ float dv[BSIZE];
    int t = threadIdx.x, b = blockIdx.x;
    int base = padBase[b];
    int n0 = b * BSIZE + t, n1 = n0 + 256;
    int d0 = (n0 < N_NODES) ? deg[n0] : 0;
    int d1 = (n1 < N_NODES) ? deg[n1] : 0;
    int p0 = ((d0 + 15) >> 4) << 4;
    int p1 = ((d1 + 15) >> 4) << 4;
    sc[t] = p0; sc[t + 256] = p1;
    dv[t] = (n0 < N_NODES) ? dinv[n0] : 0.f;
    dv[t + 256] = (n1 < N_NODES) ? dinv[n1] : 0.f;
    __syncthreads();
    for (int off = 1; off < BSIZE; off <<= 1) {
        int i0 = t, i1 = t + 256;
        int v0 = (i0 >= off) ? sc[i0 - off] : 0;
        int v1 = (i1 >= off) ? sc[i1 - off] : 0;
        __syncthreads();
        sc[i0] += v0; sc[i1] += v1;
        __syncthreads();
    }
    int off0 = base + sc[t] - p0;
    int off1 = base + sc[t + 256] - p1;
    if (n0 < N_NODES) rowptrP[n0] = off0;
    if (n1 < N_NODES) rowptrP[n1] = off1;
    cur[t] = off0; cur[t + 256] = off1;
    int padT = sc[BSIZE - 1];
    // init padded region to dummy (record 0 = src 0, coef 0)
    for (int i = base + t; i < base + padT; i += 256) edges[i] = 0;
    __syncthreads();
    int s0 = bbase[b], s1 = bbase[b + 1];
    for (int e = s0 + t; e < s1; e += 256) {
        unsigned r = bkt[e];
        int dl = (int)(r & (BSIZE - 1));
        int s = (int)(r >> BSHIFT);
        int p = atomicAdd(&cur[dl], 1);
        float c = dv[dl] * dinv[s];
        unsigned short cb = __builtin_bit_cast(unsigned short, (f16)c);
        edges[p] = ((unsigned)s << 15) | (unsigned)(cb & 0x7FFFu);
    }
}

// ---------------- FUSED layer 1: Agg(x) (thread-per-node) + (Nx4)@(4x128) GEMM, fp8 out -----
__global__ __launch_bounds__(256) void k_aggxg(const float4* __restrict__ x,
                                               const int* __restrict__ rowptrP,
                                               const unsigned* __restrict__ edges,
                                               const float* __restrict__ dinv,
                                               const float* __restrict__ W1, const float* __restrict__ b1,
                                               unsigned* __restrict__ hA /* fp8 rows, as u32 */) {
    __shared__ float4 sx[256];
    __shared__ float sW[4 * HID];
    __shared__ float sb[HID];
    int tid = threadIdx.x;
    sW[tid] = W1[tid];
    sW[tid + 256] = W1[tid + 256];
    if (tid < HID) sb[tid] = b1[tid];

    int i = blockIdx.x * 256 + tid;
    float4 agg = make_float4(0.f, 0.f, 0.f, 0.f);
    if (i < N_NODES) {
        float di = dinv[i];
        float4 xv = x[i];
        float c0 = di * di;
        agg.x = c0 * xv.x; agg.y = c0 * xv.y; agg.z = c0 * xv.z; agg.w = c0 * xv.w;
        int beg = rowptrP[i], end = rowptrP[i + 1];
        for (int e = beg; e < end; ++e) {
            unsigned r = edges[e];
            float c = rec_coef(r);
            float4 v = x[r >> 15];
            agg.x = fmaf(c, v.x, agg.x); agg.y = fmaf(c, v.y, agg.y);
            agg.z = fmaf(c, v.z, agg.z); agg.w = fmaf(c, v.w, agg.w);
        }
    }
    sx[tid] = agg;
    __syncthreads();

    int node0 = blockIdx.x * 256;
#pragma unroll
    for (int it = 0; it < 32; ++it) {
        int id = it * 256 + tid;
        int n = id >> 5;          // local node 0..255
        int g = id & 31;          // column group (4 cols)
        int node = node0 + n;
        if (node >= N_NODES) continue;
        float4 a = sx[n];
        float c[4];
#pragma unroll
        for (int j = 0; j < 4; ++j) {
            int col = g * 4 + j;
            float v = sb[col];
            v = fmaf(a.x, sW[col],           v);
            v = fmaf(a.y, sW[HID + col],     v);
            v = fmaf(a.z, sW[2 * HID + col], v);
            v = fmaf(a.w, sW[3 * HID + col], v);
            c[j] = fmaxf(v, 0.0f);
        }
        unsigned lo = __hip_fp8x2_e4m3(make_float2(c[0], c[1])).__x;
        unsigned hi = __hip_fp8x2_e4m3(make_float2(c[2], c[3])).__x;
        hA[node * 32 + g] = lo | (hi << 16);
    }
}

// ---------------- CSR aggregation, fp8 payload, padded edge lists (no tail) ------------------
// Wave = 4 groups x 16 lanes; group g = edge slot, sublane l = features 8l..8l+7.
// Edge lists are padded to multiples of 16 with dummy records (coef 0, src 0 -> hot line),
// so the loop has no serialized tail; all 4 gathers per iter are independent.
__global__ __launch_bounds__(256) void k_agg8p(const unsigned* __restrict__ h8,
                                               const int* __restrict__ rowptrP,
                                               const unsigned* __restrict__ edges,
                                               const float* __restrict__ dinv,
                                               f16* __restrict__ out) {
    int node = blockIdx.x * 4 + (threadIdx.x >> 6);
    if (node >= N_NODES) return;
    int lane = threadIdx.x & 63;
    int g = lane >> 4;
    int l = lane & 15;
    int beg = rowptrP[node], end = rowptrP[node + 1];

    float acc[8];
    {
        float di = dinv[node];
        float c0 = (g == 0) ? di * di : 0.0f;
        uint2 v = *(const uint2*)(h8 + (size_t)node * 32 + l * 2);
        float2 p0 = fp8x2_to_f32x2((unsigned short)(v.x & 0xFFFFu));
        float2 p1 = fp8x2_to_f32x2((unsigned short)(v.x >> 16));
        float2 p2 = fp8x2_to_f32x2((unsigned short)(v.y & 0xFFFFu));
        float2 p3 = fp8x2_to_f32x2((unsigned short)(v.y >> 16));
        acc[0] = c0 * p0.x; acc[1] = c0 * p0.y;
        acc[2] = c0 * p1.x; acc[3] = c0 * p1.y;
        acc[4] = c0 * p2.x; acc[5] = c0 * p2.y;
        acc[6] = c0 * p3.x; acc[7] = c0 * p3.y;
    }

    for (int e = beg; e < end; e += 16) {
        unsigned rec16 = edges[e + l];     // lanes 0-15 hold records e..e+15 (groups replicate)
#pragma unroll
        for (int i = 0; i < 4; ++i) {
            unsigned rec = __shfl(rec16, i * 4 + g, 64);
            float c = rec_coef(rec);
            uint2 v = *(const uint2*)(h8 + (size_t)(rec >> 15) * 32 + l * 2);
            fma8(c, v, acc);
        }
    }

#pragma unroll
    for (int j = 0; j < 8; ++j) {
        acc[j] += __shfl_xor(acc[j], 16, 64);
        acc[j] += __shfl_xor(acc[j], 32, 64);
    }
    if (lane < 16) {
        f16x8 o;
#pragma unroll
        for (int j = 0; j < 8; ++j) o[j] = (f16)acc[j];
        *(f16x8*)(out + (size_t)node * HID + l * 8) = o;
    }
}

// ---------------- pack 3x W (128x128 fp32) into MFMA B-fragment order, fp16, one launch -----
__global__ __launch_bounds__(256) void k_packW3(const float* __restrict__ W2, const float* __restrict__ W3,
                                                const float* __restrict__ W4, f16* __restrict__ Wp) {
    int idx = blockIdx.x * 256 + threadIdx.x;   // 192 blocks x 256 = 49152 = 3 * 16384
    int which = idx >> 14;
    int r = idx & 16383;
    const float* W = (which == 0) ? W2 : (which == 1) ? W3 : W4;
    int j  = r & 7;
    int L  = (r >> 3) & 63;
    int ks = (r >> 9) & 3;
    int ct = r >> 11;
    int k = ks * 32 + (L >> 4) * 8 + j;
    int n = ct * 16 + (L & 15);
    Wp[idx] = (f16)W[k * HID + n];
}

// ---------------- main GEMM via MFMA: (N x 128 f16) @ Wp + bias, ReLU; fp8 or fp16 out -------
template <bool FP8OUT>
__global__ __launch_bounds__(256) void k_gemm_mfma(const f16* __restrict__ A, const f16* __restrict__ Wp,
                                                   const float* __restrict__ bias, void* __restrict__ outv) {
    int wave = threadIdx.x >> 6;
    int lane = threadIdx.x & 63;
    int row0 = blockIdx.x * 64 + wave * 16;
    if (row0 >= N_NODES) return;
    int m = lane & 15;
    int q = lane >> 4;
    const f16* Arow = A + (size_t)(row0 + m) * HID + q * 8;

    f32x4 acc[8];
#pragma unroll
    for (int t = 0; t < 8; ++t) acc[t] = (f32x4){0.f, 0.f, 0.f, 0.f};

#pragma unroll
    for (int ks = 0; ks < 4; ++ks) {
        f16x8 a = *(const f16x8*)(Arow + ks * 32);
#pragma unroll
        for (int t = 0; t < 8; ++t) {
            f16x8 b = *(const f16x8*)(Wp + ((size_t)(t * 4 + ks) * 64 + lane) * 8);
            acc[t] = __builtin_amdgcn_mfma_f32_16x16x32_f16(a, b, acc[t], 0, 0, 0);
        }
    }

    int orow = row0 + q * 4;
#pragma unroll
    for (int t = 0; t < 8; ++t) {
        float bb = bias[t * 16 + m];
#pragma unroll
        for (int r = 0; r < 4; ++r) {
            float val = fmaxf(acc[t][r] + bb, 0.0f);
            if constexpr (FP8OUT) {
                __hip_fp8_e4m3* out8 = (__hip_fp8_e4m3*)outv;
                out8[(size_t)(orow + r) * HID + t * 16 + m] = __hip_fp8_e4m3(val);
            } else {
                f16* out = (f16*)outv;
                out[(size_t)(orow + r) * HID + t * 16 + m] = (f16)val;
            }
        }
    }
}

// ---------------- pooling pass 1: per (graph, segment) partial sums, fp32, deterministic -----
__device__ __forceinline__ int lower_bound_batch(const int* __restrict__ batch, int val) {
    int lo = 0, hi = N_NODES;
    while (lo < hi) { int m = (lo + hi) >> 1; if (batch[m] < val) lo = m + 1; else hi = m; }
    return lo;
}

__global__ __launch_bounds__(128) void k_pool1(const f16* __restrict__ h, const int* __restrict__ batch,
                                               float* __restrict__ partials) {
    int g = blockIdx.x / POOL_SEG;
    int s = blockIdx.x % POOL_SEG;
    int f = threadIdx.x;
    int beg = lower_bound_batch(batch, g);
    int end = lower_bound_batch(batch, g + 1);
    int len = end - beg;
    int sb = beg + (int)(((long long)len * s) / POOL_SEG);
    int se = beg + (int)(((long long)len * (s + 1)) / POOL_SEG);
    float acc = 0.0f;
    for (int i = sb; i < se; ++i) acc += (float)h[i * HID + f];
    partials[(size_t)blockIdx.x * HID + f] = acc;
}

// ---------------- pooling pass 2 + head fused ---------------
__global__ __launch_bounds__(128) void k_pool2h(const float* __restrict__ partials,
                                                const int* __restrict__ batch,
                                                const float* __restrict__ Wl, const float* __restrict__ bl,
                                                float* __restrict__ out) {
    __shared__ float sp[HID];
    int g = blockIdx.x;
    int f = threadIdx.x;
    float acc = 0.0f;
#pragma unroll
    for (int s = 0; s < POOL_SEG; ++s)
        acc += partials[(size_t)(g * POOL_SEG + s) * HID + f];
    int beg = lower_bound_batch(batch, g);
    int end = lower_bound_batch(batch, g + 1);
    sp[f] = acc / fmaxf((float)(end - beg), 1.0f);
    __syncthreads();
    if (f < N_CLS) {
        float v = bl[f];
        for (int k = 0; k < HID; ++k) v = fmaf(sp[k], Wl[k * N_CLS + f], v);
        out[g * N_CLS + f] = 1.0f / (1.0f + expf(-v));
    }
}

extern "C" void kernel_launch(void* const* d_in, const int* in_sizes, int n_in,
                              void* d_out, int out_size, void* d_ws, size_t ws_size,
                              hipStream_t stream) {
    const float* x     = (const float*)d_in[0];
    const int*   ei    = (const int*)d_in[1];
    const int*   batch = (const int*)d_in[2];
    const float* W1 = (const float*)d_in[3];  const float* b1 = (const float*)d_in[4];
    const float* W2 = (const float*)d_in[5];  const float* b2 = (const float*)d_in[6];
    const float* W3 = (const float*)d_in[7];  const float* b3 = (const float*)d_in[8];
    const float* W4 = (const float*)d_in[9];  const float* b4 = (const float*)d_in[10];
    const float* Wl = (const float*)d_in[11]; const float* bl = (const float*)d_in[12];
    float* out = (float*)d_out;

    const size_t EPAD = (size_t)N_EDGES + (size_t)N_NODES * 16;   // padded edge capacity

    char* p = (char*)d_ws;
    auto alloc = [&](size_t bytes) { char* r = p; p += (bytes + 255) & ~(size_t)255; return (void*)r; };
    int*      C       = (int*)     alloc((size_t)NCHUNK * NBUK * 4);
    int*      Off     = (int*)     alloc((size_t)NCHUNK * NBUK * 4);
    int*      bbase   = (int*)     alloc((size_t)(NBUK + 1) * 4);
    int*      padTot  = (int*)     alloc((size_t)NBUK * 4);
    int*      padBase = (int*)     alloc((size_t)(NBUK + 1) * 4);
    unsigned* bkt     = (unsigned*)alloc((size_t)N_EDGES * 4);
    int*      deg     = (int*)     alloc((size_t)N_NODES * 4);
    int*      rowptrP = (int*)     alloc((size_t)(N_NODES + 1) * 4);
    float*    dinv    = (float*)   alloc((size_t)N_NODES * 4);
    unsigned* edges   = (unsigned*)alloc(EPAD * 4);
    unsigned* hA      = (unsigned*)alloc((size_t)N_NODES * HID);      // fp8 gather source
    f16*      hB      = (f16*)     alloc((size_t)N_NODES * HID * 2);  // fp16 agg out / GEMM A
    f16*      h4      = (f16*)     alloc((size_t)N_NODES * HID * 2);  // fp16 final layer out
    float*    parts   = (float*)   alloc((size_t)N_GRAPH * POOL_SEG * HID * 4);
    f16*      Wp      = (f16*)     alloc((size_t)3 * HID * HID * 2);
    f16*      Wp2 = Wp;
    f16*      Wp3 = Wp + HID * HID;
    f16*      Wp4 = Wp + 2 * HID * HID;

    const int* srcv = ei;              // edge_index[0]
    const int* dstv = ei + N_EDGES;    // edge_index[1]

    const int nb = (N_NODES + 255) / 256;   // 391

    // CSR build: bucketed, no global atomics, padded-to-16 rows, coef fused into scatter
    k_bc     <<<NCHUNK, 256, 0, stream>>>(dstv, C);
    k_bscan  <<<1, 256, 0, stream>>>(C, Off, bbase);
    k_scatter<<<NCHUNK, 256, 0, stream>>>(srcv, dstv, Off, bbase, bkt);
    k_hist2  <<<NBUK, 256, 0, stream>>>(bkt, bbase, deg, dinv, padTot);
    k_pscan  <<<1, 256, 0, stream>>>(padTot, padBase, rowptrP);
    k_local2 <<<NBUK, 256, 0, stream>>>(bkt, bbase, deg, dinv, padBase, rowptrP, edges);

    k_packW3<<<192, 256, 0, stream>>>(W2, W3, W4, Wp);

    // layer 1: fused Agg(x) + (Nx4)@(4x128) GEMM, fp8 out
    k_aggxg<<<nb, 256, 0, stream>>>((const float4*)x, rowptrP, edges, dinv, W1, b1, hA);

    // layers 2..4: Agg (fp8 gather, padded, no tail) then MFMA GEMM (+bias, ReLU)
    const int ggrid = (N_NODES + 63) / 64;   // 1563
    k_agg8p<<<N_NODES / 4, 256, 0, stream>>>(hA, rowptrP, edges, dinv, hB);
    k_gemm_mfma<true ><<<ggrid, 256, 0, stream>>>(hB, Wp2, b2, hA);
    k_agg8p<<<N_NODES / 4, 256, 0, stream>>>(hA, rowptrP, edges, dinv, hB);
    k_gemm_mfma<true ><<<ggrid, 256, 0, stream>>>(hB, Wp3, b3, hA);
    k_agg8p<<<N_NODES / 4, 256, 0, stream>>>(hA, rowptrP, edges, dinv, hB);
    k_gemm_mfma<false><<<ggrid, 256, 0, stream>>>(hB, Wp4, b4, h4);

    k_pool1 <<<N_GRAPH * POOL_SEG, 128, 0, stream>>>(h4, batch, parts);
    k_pool2h<<<N_GRAPH, 128, 0, stream>>>(parts, batch, Wl, bl, out);
}

// Round 11
// 375.045 us; speedup vs baseline: 1.6949x; 1.0052x over previous
//
#include <hip/hip_runtime.h>
#include <hip/hip_fp8.h>
#include <math.h>

#define N_NODES 100000
#define N_EDGES 1600000
#define F_IN    4
#define HID     128
#define N_CLS   5
#define N_GRAPH 256
#define POOL_SEG 8

#define BSHIFT   9
#define BSIZE    512
#define NBUK     196            // ceil(100000 / 512)
#define NCHUNK   200
#define CHUNK    8000           // 200 * 8000 = 1.6M exactly

typedef _Float16 f16;
typedef _Float16 f16x2 __attribute__((ext_vector_type(2)));
typedef _Float16 f16x8 __attribute__((ext_vector_type(8)));
typedef float f32x4 __attribute__((ext_vector_type(4)));
typedef float f32x2 __attribute__((ext_vector_type(2)));

// decode 4-byte edge record: [src:17 | coef-f16-positive:15]; record 0 == dummy (src 0, coef 0)
__device__ __forceinline__ float rec_coef(unsigned r) {
    return (float)__builtin_bit_cast(_Float16, (unsigned short)(r & 0x7FFFu));
}

__device__ __forceinline__ f32x2 fp8x2_to_v2(unsigned short raw) {
    __hip_fp8x2_e4m3 t;
    t.__x = raw;
    float2 f = static_cast<float2>(t);
    return (f32x2){f.x, f.y};
}

// 8 fp8 (uint2) -> packed fma into acc[0..3] (f32x2 each) with scalar coef c
__device__ __forceinline__ void fma8p(float c, uint2 v, f32x2* acc) {
    f32x2 cc = {c, c};
    acc[0] = __builtin_elementwise_fma(cc, fp8x2_to_v2((unsigned short)(v.x & 0xFFFFu)), acc[0]);
    acc[1] = __builtin_elementwise_fma(cc, fp8x2_to_v2((unsigned short)(v.x >> 16)),     acc[1]);
    acc[2] = __builtin_elementwise_fma(cc, fp8x2_to_v2((unsigned short)(v.y & 0xFFFFu)), acc[2]);
    acc[3] = __builtin_elementwise_fma(cc, fp8x2_to_v2((unsigned short)(v.y >> 16)),     acc[3]);
}

// ---------------- CSR build step 1: per-(chunk,bucket) counts via LDS histogram -------------
__global__ __launch_bounds__(256) void k_bc(const int* __restrict__ dst, int* __restrict__ C) {
    __shared__ int cnt[NBUK];
    int t = threadIdx.x;
    if (t < NBUK) cnt[t] = 0;
    __syncthreads();
    int base = blockIdx.x * CHUNK;
#pragma unroll
    for (int it = 0; it < 32; ++it) {
        int idx = it * 256 + t;
        if (idx < CHUNK) atomicAdd(&cnt[dst[base + idx] >> BSHIFT], 1);
    }
    __syncthreads();
    if (t < NBUK) C[blockIdx.x * NBUK + t] = cnt[t];
}

// ---------------- step 2: offsets. Off[c][b] = prefix over chunks; bbase = bucket bases -----
__global__ __launch_bounds__(256) void k_bscan(const int* __restrict__ C, int* __restrict__ Off,
                                               int* __restrict__ bbase) {
    __shared__ int s[256];
    int b = threadIdx.x;
    int tot = 0;
    if (b < NBUK) {
        for (int c = 0; c < NCHUNK; ++c) {
            Off[c * NBUK + b] = tot;
            tot += C[c * NBUK + b];
        }
    }
    s[b] = (b < NBUK) ? tot : 0;
    __syncthreads();
    for (int off = 1; off < 256; off <<= 1) {
        int v = (b >= off) ? s[b - off] : 0;
        __syncthreads();
        s[b] += v;
        __syncthreads();
    }
    if (b < NBUK) bbase[b] = s[b] - tot;   // exclusive
    if (b == 0) bbase[NBUK] = N_EDGES;
}

// ---------------- step 3: scatter packed records into bucket-grouped array ------------------
// record: (src:17)<<9 | (dst & 511)
__global__ __launch_bounds__(256) void k_scatter(const int* __restrict__ src, const int* __restrict__ dst,
                                                 const int* __restrict__ Off, const int* __restrict__ bbase,
                                                 unsigned* __restrict__ bkt) {
    __shared__ int cur[NBUK];
    int t = threadIdx.x;
    if (t < NBUK) cur[t] = bbase[t] + Off[blockIdx.x * NBUK + t];
    __syncthreads();
    int base = blockIdx.x * CHUNK;
#pragma unroll
    for (int it = 0; it < 32; ++it) {
        int idx = it * 256 + t;
        if (idx < CHUNK) {
            int s = src[base + idx], d = dst[base + idx];
            int b = d >> BSHIFT;
            int p = atomicAdd(&cur[b], 1);
            bkt[p] = ((unsigned)s << BSHIFT) | (unsigned)(d & (BSIZE - 1));
        }
    }
}

// ---------------- step 4: per-bucket degree hist -> deg, dinv, padded bucket total ----------
__global__ __launch_bounds__(256) void k_hist2(const unsigned* __restrict__ bkt,
                                               const int* __restrict__ bbase,
                                               int* __restrict__ deg, float* __restrict__ dinv,
                                               int* __restrict__ padTot) {
    __shared__ int hist[BSIZE];
    __shared__ int tot;
    int t = threadIdx.x, b = blockIdx.x;
    hist[t] = 0; hist[t + 256] = 0;
    if (t == 0) tot = 0;
    __syncthreads();
    int s0 = bbase[b], s1 = bbase[b + 1];
    for (int e = s0 + t; e < s1; e += 256) atomicAdd(&hist[bkt[e] & (BSIZE - 1)], 1);
    __syncthreads();
    int loc = 0;
#pragma unroll
    for (int h = 0; h < 2; ++h) {
        int l = t + h * 256;
        int node = b * BSIZE + l;
        int d = hist[l];
        if (node < N_NODES) {
            deg[node] = d;
            dinv[node] = rsqrtf((float)d + 1.0f);
        }
        loc += (d + 15) >> 4;
    }
    atomicAdd(&tot, loc);
    __syncthreads();
    if (t == 0) padTot[b] = tot << 4;
}

// ---------------- step 5: scan padded bucket totals -> padded bases ------------------------
__global__ __launch_bounds__(256) void k_pscan(const int* __restrict__ padTot, int* __restrict__ padBase,
                                               int* __restrict__ rowptrP) {
    __shared__ int s[256];
    int b = threadIdx.x;
    int v = (b < NBUK) ? padTot[b] : 0;
    s[b] = v;
    __syncthreads();
    for (int off = 1; off < 256; off <<= 1) {
        int u = (b >= off) ? s[b - off] : 0;
        __syncthreads();
        s[b] += u;
        __syncthreads();
    }
    if (b < NBUK) padBase[b] = s[b] - v;
    if (b == 0) {
        padBase[NBUK] = s[NBUK - 1];
        rowptrP[N_NODES] = s[NBUK - 1];
    }
}

// ---------------- step 6: per-bucket padded CSR + coef fused; dummy slots = record 0 --------
__global__ __launch_bounds__(256) void k_local2(const unsigned* __restrict__ bkt,
                                                const int* __restrict__ bbase,
                                                const int* __restrict__ deg,
                                                const float* __restrict__ dinv,
                                                const int* __restrict__ padBase,
                                                int* __restrict__ rowptrP,
                                                unsigned* __restrict__ edges) {
    __shared__ int sc[BSIZE];
    __shared__ int cur[BSIZE];
    __shared__ float dv[BSIZE];
    int t = threadIdx.x, b = blockIdx.x;
    int base = padBase[b];
    int n0 = b * BSIZE + t, n1 = n0 + 256;
    int d0 = (n0 < N_NODES) ? deg[n0] : 0;
    int d1 = (n1 < N_NODES) ? deg[n1] : 0;
    int p0 = ((d0 + 15) >> 4) << 4;
    int p1 = ((d1 + 15) >> 4) << 4;
    sc[t] = p0; sc[t + 256] = p1;
    dv[t] = (n0 < N_NODES) ? dinv[n0] : 0.f;
    dv[t + 256] = (n1 < N_NODES) ? dinv[n1] : 0.f;
    __syncthreads();
    for (int off = 1; off < BSIZE; off <<= 1) {
        int i0 = t, i1 = t + 256;
        int v0 = (i0 >= off) ? sc[i0 - off] : 0;
        int v1 = (i1 >= off) ? sc[i1 - off] : 0;
        __syncthreads();
        sc[i0] += v0; sc[i1] += v1;
        __syncthreads();
    }
    int off0 = base + sc[t] - p0;
    int off1 = base + sc[t + 256] - p1;
    if (n0 < N_NODES) rowptrP[n0] = off0;
    if (n1 < N_NODES) rowptrP[n1] = off1;
    cur[t] = off0; cur[t + 256] = off1;
    int padT = sc[BSIZE - 1];
    // init padded region to dummy (record 0 = src 0, coef 0)
    for (int i = base + t; i < base + padT; i += 256) edges[i] = 0;
    __syncthreads();
    int s0 = bbase[b], s1 = bbase[b + 1];
    for (int e = s0 + t; e < s1; e += 256) {
        unsigned r = bkt[e];
        int dl = (int)(r & (BSIZE - 1));
        int s = (int)(r >> BSHIFT);
        int p = atomicAdd(&cur[dl], 1);
        float c = dv[dl] * dinv[s];
        unsigned short cb = __builtin_bit_cast(unsigned short, (f16)c);
        edges[p] = ((unsigned)s << 15) | (unsigned)(cb & 0x7FFFu);
    }
}

// ---------------- layer-1 aggregation, wave-parallel: 16 lanes per node ---------------------
// Block = 256 thr = 4 waves = 16 nodes. Lane l of a node-group handles edge slots l, l+16, ...
// (rows padded to x16 -> no tail), gathers the full 16-B x row, accumulates float4; shfl-xor
// reduce over the 16 lanes; lane 0 adds the self term and writes xagg.
__global__ __launch_bounds__(256) void k_aggx4(const float4* __restrict__ x,
                                               const int* __restrict__ rowptrP,
                                               const unsigned* __restrict__ edges,
                                               const float* __restrict__ dinv,
                                               float4* __restrict__ xagg) {
    int t = threadIdx.x;
    int grp = t >> 4;             // 0..15 within block
    int l = t & 15;
    int node = blockIdx.x * 16 + grp;   // grid 6250 * 16 = 100000 exactly
    int beg = rowptrP[node], end = rowptrP[node + 1];
    float ax = 0.f, ay = 0.f, az = 0.f, aw = 0.f;
    for (int e = beg + l; e < end; e += 16) {
        unsigned r = edges[e];
        float c = rec_coef(r);
        float4 v = x[r >> 15];
        ax = fmaf(c, v.x, ax); ay = fmaf(c, v.y, ay);
        az = fmaf(c, v.z, az); aw = fmaf(c, v.w, aw);
    }
#pragma unroll
    for (int off = 1; off < 16; off <<= 1) {
        ax += __shfl_xor(ax, off, 64);
        ay += __shfl_xor(ay, off, 64);
        az += __shfl_xor(az, off, 64);
        aw += __shfl_xor(aw, off, 64);
    }
    if (l == 0) {
        float di = dinv[node];
        float c0 = di * di;
        float4 xv = x[node];
        xagg[node] = make_float4(fmaf(c0, xv.x, ax), fmaf(c0, xv.y, ay),
                                 fmaf(c0, xv.z, az), fmaf(c0, xv.w, aw));
    }
}

// ---------------- layer-1 GEMM: (N x 4) @ (4 x 128) + bias, ReLU, fp8 out -------------------
__global__ __launch_bounds__(256) void k_gemm4(const float4* __restrict__ xagg,
                                               const float* __restrict__ W1, const float* __restrict__ b1,
                                               unsigned* __restrict__ hA) {
    __shared__ float4 sx[256];
    __shared__ float sW[4 * HID];
    __shared__ float sb[HID];
    int tid = threadIdx.x;
    sW[tid] = W1[tid];
    sW[tid + 256] = W1[tid + 256];
    if (tid < HID) sb[tid] = b1[tid];
    int i = blockIdx.x * 256 + tid;
    sx[tid] = (i < N_NODES) ? xagg[i] : make_float4(0.f, 0.f, 0.f, 0.f);
    __syncthreads();

    int node0 = blockIdx.x * 256;
#pragma unroll
    for (int it = 0; it < 32; ++it) {
        int id = it * 256 + tid;
        int n = id >> 5;          // local node 0..255
        int g = id & 31;          // column group (4 cols)
        int node = node0 + n;
        if (node >= N_NODES) continue;
        float4 a = sx[n];
        float c[4];
#pragma unroll
        for (int j = 0; j < 4; ++j) {
            int col = g * 4 + j;
            float v = sb[col];
            v = fmaf(a.x, sW[col],           v);
            v = fmaf(a.y, sW[HID + col],     v);
            v = fmaf(a.z, sW[2 * HID + col], v);
            v = fmaf(a.w, sW[3 * HID + col], v);
            c[j] = fmaxf(v, 0.0f);
        }
        unsigned lo = __hip_fp8x2_e4m3(make_float2(c[0], c[1])).__x;
        unsigned hi = __hip_fp8x2_e4m3(make_float2(c[2], c[3])).__x;
        hA[node * 32 + g] = lo | (hi << 16);
    }
}

// ---------------- CSR aggregation, fp8 payload, padded rows, packed-f32 math ----------------
__global__ __launch_bounds__(256) void k_agg8p(const unsigned* __restrict__ h8,
                                               const int* __restrict__ rowptrP,
                                               const unsigned* __restrict__ edges,
                                               const float* __restrict__ dinv,
                                               f16* __restrict__ out) {
    int node = blockIdx.x * 4 + (threadIdx.x >> 6);
    if (node >= N_NODES) return;
    int lane = threadIdx.x & 63;
    int g = lane >> 4;
    int l = lane & 15;
    int beg = rowptrP[node], end = rowptrP[node + 1];
    const char* hp = (const char*)h8 + l * 8;   // per-lane feature base

    f32x2 acc[4];
    {
        float di = dinv[node];
        float c0 = (g == 0) ? di * di : 0.0f;
        f32x2 cc = {c0, c0};
        uint2 v = *(const uint2*)(hp + ((size_t)node << 7));
        acc[0] = cc * fp8x2_to_v2((unsigned short)(v.x & 0xFFFFu));
        acc[1] = cc * fp8x2_to_v2((unsigned short)(v.x >> 16));
        acc[2] = cc * fp8x2_to_v2((unsigned short)(v.y & 0xFFFFu));
        acc[3] = cc * fp8x2_to_v2((unsigned short)(v.y >> 16));
    }

    for (int e = beg; e < end; e += 16) {
        unsigned rec16 = edges[e + l];     // lanes 0-15 hold records e..e+15 (groups replicate)
#pragma unroll
        for (int i = 0; i < 4; ++i) {
            unsigned rec = __shfl(rec16, i * 4 + g, 64);
            float c = rec_coef(rec);
            uint2 v = *(const uint2*)(hp + ((rec >> 8) & 0xFFFFFF80u));
            fma8p(c, v, acc);
        }
    }

    float a0 = acc[0][0], a1 = acc[0][1], a2 = acc[1][0], a3 = acc[1][1];
    float a4 = acc[2][0], a5 = acc[2][1], a6 = acc[3][0], a7 = acc[3][1];
#pragma unroll
    for (int j = 0; j < 1; ++j) { }   // keep structure simple
    a0 += __shfl_xor(a0, 16, 64); a0 += __shfl_xor(a0, 32, 64);
    a1 += __shfl_xor(a1, 16, 64); a1 += __shfl_xor(a1, 32, 64);
    a2 += __shfl_xor(a2, 16, 64); a2 += __shfl_xor(a2, 32, 64);
    a3 += __shfl_xor(a3, 16, 64); a3 += __shfl_xor(a3, 32, 64);
    a4 += __shfl_xor(a4, 16, 64); a4 += __shfl_xor(a4, 32, 64);
    a5 += __shfl_xor(a5, 16, 64); a5 += __shfl_xor(a5, 32, 64);
    a6 += __shfl_xor(a6, 16, 64); a6 += __shfl_xor(a6, 32, 64);
    a7 += __shfl_xor(a7, 16, 64); a7 += __shfl_xor(a7, 32, 64);
    if (lane < 16) {
        f16x8 o;
        o[0] = (f16)a0; o[1] = (f16)a1; o[2] = (f16)a2; o[3] = (f16)a3;
        o[4] = (f16)a4; o[5] = (f16)a5; o[6] = (f16)a6; o[7] = (f16)a7;
        *(f16x8*)(out + (size_t)node * HID + l * 8) = o;
    }
}

// ---------------- pack 3x W (128x128 fp32) into MFMA B-fragment order, fp16, one launch -----
__global__ __launch_bounds__(256) void k_packW3(const float* __restrict__ W2, const float* __restrict__ W3,
                                                const float* __restrict__ W4, f16* __restrict__ Wp) {
    int idx = blockIdx.x * 256 + threadIdx.x;   // 192 blocks x 256 = 49152 = 3 * 16384
    int which = idx >> 14;
    int r = idx & 16383;
    const float* W = (which == 0) ? W2 : (which == 1) ? W3 : W4;
    int j  = r & 7;
    int L  = (r >> 3) & 63;
    int ks = (r >> 9) & 3;
    int ct = r >> 11;
    int k = ks * 32 + (L >> 4) * 8 + j;
    int n = ct * 16 + (L & 15);
    Wp[idx] = (f16)W[k * HID + n];
}

// ---------------- main GEMM via MFMA: (N x 128 f16) @ Wp + bias, ReLU; fp8 or fp16 out -------
template <bool FP8OUT>
__global__ __launch_bounds__(256) void k_gemm_mfma(const f16* __restrict__ A, const f16* __restrict__ Wp,
                                                   const float* __restrict__ bias, void* __restrict__ outv) {
    int wave = threadIdx.x >> 6;
    int lane = threadIdx.x & 63;
    int row0 = blockIdx.x * 64 + wave * 16;
    if (row0 >= N_NODES) return;
    int m = lane & 15;
    int q = lane >> 4;
    const f16* Arow = A + (size_t)(row0 + m) * HID + q * 8;

    f32x4 acc[8];
#pragma unroll
    for (int t = 0; t < 8; ++t) acc[t] = (f32x4){0.f, 0.f, 0.f, 0.f};

#pragma unroll
    for (int ks = 0; ks < 4; ++ks) {
        f16x8 a = *(const f16x8*)(Arow + ks * 32);
#pragma unroll
        for (int t = 0; t < 8; ++t) {
            f16x8 b = *(const f16x8*)(Wp + ((size_t)(t * 4 + ks) * 64 + lane) * 8);
            acc[t] = __builtin_amdgcn_mfma_f32_16x16x32_f16(a, b, acc[t], 0, 0, 0);
        }
    }

    int orow = row0 + q * 4;
#pragma unroll
    for (int t = 0; t < 8; ++t) {
        float bb = bias[t * 16 + m];
#pragma unroll
        for (int r = 0; r < 4; ++r) {
            float val = fmaxf(acc[t][r] + bb, 0.0f);
            if constexpr (FP8OUT) {
                __hip_fp8_e4m3* out8 = (__hip_fp8_e4m3*)outv;
                out8[(size_t)(orow + r) * HID + t * 16 + m] = __hip_fp8_e4m3(val);
            } else {
                f16* out = (f16*)outv;
                out[(size_t)(orow + r) * HID + t * 16 + m] = (f16)val;
            }
        }
    }
}

// ---------------- pooling pass 1: per (graph, segment) partial sums, fp32, deterministic -----
__device__ __forceinline__ int lower_bound_batch(const int* __restrict__ batch, int val) {
    int lo = 0, hi = N_NODES;
    while (lo < hi) { int m = (lo + hi) >> 1; if (batch[m] < val) lo = m + 1; else hi = m; }
    return lo;
}

__global__ __launch_bounds__(128) void k_pool1(const f16* __restrict__ h, const int* __restrict__ batch,
                                               float* __restrict__ partials) {
    int g = blockIdx.x / POOL_SEG;
    int s = blockIdx.x % POOL_SEG;
    int f = threadIdx.x;
    int beg = lower_bound_batch(batch, g);
    int end = lower_bound_batch(batch, g + 1);
    int len = end - beg;
    int sb = beg + (int)(((long long)len * s) / POOL_SEG);
    int se = beg + (int)(((long long)len * (s + 1)) / POOL_SEG);
    float acc = 0.0f;
    for (int i = sb; i < se; ++i) acc += (float)h[i * HID + f];
    partials[(size_t)blockIdx.x * HID + f] = acc;
}

// ---------------- pooling pass 2 + head fused ---------------
__global__ __launch_bounds__(128) void k_pool2h(const float* __restrict__ partials,
                                                const int* __restrict__ batch,
                                                const float* __restrict__ Wl, const float* __restrict__ bl,
                                                float* __restrict__ out) {
    __shared__ float sp[HID];
    int g = blockIdx.x;
    int f = threadIdx.x;
    float acc = 0.0f;
#pragma unroll
    for (int s = 0; s < POOL_SEG; ++s)
        acc += partials[(size_t)(g * POOL_SEG + s) * HID + f];
    int beg = lower_bound_batch(batch, g);
    int end = lower_bound_batch(batch, g + 1);
    sp[f] = acc / fmaxf((float)(end - beg), 1.0f);
    __syncthreads();
    if (f < N_CLS) {
        float v = bl[f];
        for (int k = 0; k < HID; ++k) v = fmaf(sp[k], Wl[k * N_CLS + f], v);
        out[g * N_CLS + f] = 1.0f / (1.0f + expf(-v));
    }
}

extern "C" void kernel_launch(void* const* d_in, const int* in_sizes, int n_in,
                              void* d_out, int out_size, void* d_ws, size_t ws_size,
                              hipStream_t stream) {
    const float* x     = (const float*)d_in[0];
    const int*   ei    = (const int*)d_in[1];
    const int*   batch = (const int*)d_in[2];
    const float* W1 = (const float*)d_in[3];  const float* b1 = (const float*)d_in[4];
    const float* W2 = (const float*)d_in[5];  const float* b2 = (const float*)d_in[6];
    const float* W3 = (const float*)d_in[7];  const float* b3 = (const float*)d_in[8];
    const float* W4 = (const float*)d_in[9];  const float* b4 = (const float*)d_in[10];
    const float* Wl = (const float*)d_in[11]; const float* bl = (const float*)d_in[12];
    float* out = (float*)d_out;

    const size_t EPAD = (size_t)N_EDGES + (size_t)N_NODES * 16;   // padded edge capacity

    char* p = (char*)d_ws;
    auto alloc = [&](size_t bytes) { char* r = p; p += (bytes + 255) & ~(size_t)255; return (void*)r; };
    int*      C       = (int*)     alloc((size_t)NCHUNK * NBUK * 4);
    int*      Off     = (int*)     alloc((size_t)NCHUNK * NBUK * 4);
    int*      bbase   = (int*)     alloc((size_t)(NBUK + 1) * 4);
    int*      padTot  = (int*)     alloc((size_t)NBUK * 4);
    int*      padBase = (int*)     alloc((size_t)(NBUK + 1) * 4);
    unsigned* bkt     = (unsigned*)alloc((size_t)N_EDGES * 4);
    int*      deg     = (int*)     alloc((size_t)N_NODES * 4);
    int*      rowptrP = (int*)     alloc((size_t)(N_NODES + 1) * 4);
    float*    dinv    = (float*)   alloc((size_t)N_NODES * 4);
    unsigned* edges   = (unsigned*)alloc(EPAD * 4);
    float*    xagg    = (float*)   alloc((size_t)N_NODES * F_IN * 4);
    unsigned* hA      = (unsigned*)alloc((size_t)N_NODES * HID);      // fp8 gather source
    f16*      hB      = (f16*)     alloc((size_t)N_NODES * HID * 2);  // fp16 agg out / GEMM A
    f16*      h4      = (f16*)     alloc((size_t)N_NODES * HID * 2);  // fp16 final layer out
    float*    parts   = (float*)   alloc((size_t)N_GRAPH * POOL_SEG * HID * 4);
    f16*      Wp      = (f16*)     alloc((size_t)3 * HID * HID * 2);
    f16*      Wp2 = Wp;
    f16*      Wp3 = Wp + HID * HID;
    f16*      Wp4 = Wp + 2 * HID * HID;

    const int* srcv = ei;              // edge_index[0]
    const int* dstv = ei + N_EDGES;    // edge_index[1]

    const int nb = (N_NODES + 255) / 256;   // 391

    // CSR build: bucketed, no global atomics, padded-to-16 rows, coef fused into scatter
    k_bc     <<<NCHUNK, 256, 0, stream>>>(dstv, C);
    k_bscan  <<<1, 256, 0, stream>>>(C, Off, bbase);
    k_scatter<<<NCHUNK, 256, 0, stream>>>(srcv, dstv, Off, bbase, bkt);
    k_hist2  <<<NBUK, 256, 0, stream>>>(bkt, bbase, deg, dinv, padTot);
    k_pscan  <<<1, 256, 0, stream>>>(padTot, padBase, rowptrP);
    k_local2 <<<NBUK, 256, 0, stream>>>(bkt, bbase, deg, dinv, padBase, rowptrP, edges);

    k_packW3<<<192, 256, 0, stream>>>(W2, W3, W4, Wp);

    // layer 1: wave-parallel Agg(x), then (Nx4)@(4x128) GEMM, fp8 out
    k_aggx4<<<N_NODES / 16, 256, 0, stream>>>((const float4*)x, rowptrP, edges, dinv, (float4*)xagg);
    k_gemm4<<<nb, 256, 0, stream>>>((const float4*)xagg, W1, b1, hA);

    // layers 2..4: Agg (fp8 gather, padded, packed math) then MFMA GEMM (+bias, ReLU)
    const int ggrid = (N_NODES + 63) / 64;   // 1563
    k_agg8p<<<N_NODES / 4, 256, 0, stream>>>(hA, rowptrP, edges, dinv, hB);
    k_gemm_mfma<true ><<<ggrid, 256, 0, stream>>>(hB, Wp2, b2, hA);
    k_agg8p<<<N_NODES / 4, 256, 0, stream>>>(hA, rowptrP, edges, dinv, hB);
    k_gemm_mfma<true ><<<ggrid, 256, 0, stream>>>(hB, Wp3, b3, hA);
    k_agg8p<<<N_NODES / 4, 256, 0, stream>>>(hA, rowptrP, edges, dinv, hB);
    k_gemm_mfma<false><<<ggrid, 256, 0, stream>>>(hB, Wp4, b4, h4);

    k_pool1 <<<N_GRAPH * POOL_SEG, 128, 0, stream>>>(h4, batch, parts);
    k_pool2h<<<N_GRAPH, 128, 0, stream>>>(parts, batch, Wl, bl, out);
}

// Round 12
// 357.555 us; speedup vs baseline: 1.7778x; 1.0489x over previous
//
#include <hip/hip_runtime.h>
#include <hip/hip_fp8.h>
#include <math.h>

#define N_NODES 100000
#define N_EDGES 1600000
#define F_IN    4
#define HID     128
#define N_CLS   5
#define N_GRAPH 256
#define POOL_SEG 8

#define BSHIFT   9
#define BSIZE    512
#define NBUK     196            // ceil(100000 / 512)
#define NCHUNK   200
#define CHUNK    8000           // 200 * 8000 = 1.6M exactly

typedef _Float16 f16;
typedef _Float16 f16x2 __attribute__((ext_vector_type(2)));
typedef _Float16 f16x8 __attribute__((ext_vector_type(8)));
typedef float f32x4 __attribute__((ext_vector_type(4)));

// decode 4-byte edge record: [src:17 | coef-f16-positive:15]; record 0 == dummy (src 0, coef 0)
__device__ __forceinline__ float rec_coef(unsigned r) {
    return (float)__builtin_bit_cast(_Float16, (unsigned short)(r & 0x7FFFu));
}

__device__ __forceinline__ float2 fp8x2_to_f32x2(unsigned short raw) {
    __hip_fp8x2_e4m3 t;
    t.__x = raw;
    return static_cast<float2>(t);
}

// 8 fp8 values (uint2) -> fma into acc[0..7] with coefficient c
__device__ __forceinline__ void fma8(float c, uint2 v, float* acc) {
    float2 p0 = fp8x2_to_f32x2((unsigned short)(v.x & 0xFFFFu));
    float2 p1 = fp8x2_to_f32x2((unsigned short)(v.x >> 16));
    float2 p2 = fp8x2_to_f32x2((unsigned short)(v.y & 0xFFFFu));
    float2 p3 = fp8x2_to_f32x2((unsigned short)(v.y >> 16));
    acc[0] = fmaf(c, p0.x, acc[0]); acc[1] = fmaf(c, p0.y, acc[1]);
    acc[2] = fmaf(c, p1.x, acc[2]); acc[3] = fmaf(c, p1.y, acc[3]);
    acc[4] = fmaf(c, p2.x, acc[4]); acc[5] = fmaf(c, p2.y, acc[5]);
    acc[6] = fmaf(c, p3.x, acc[6]); acc[7] = fmaf(c, p3.y, acc[7]);
}

// ---------------- CSR build step 1: per-(chunk,bucket) counts via LDS histogram -------------
__global__ __launch_bounds__(256) void k_bc(const int* __restrict__ dst, int* __restrict__ C) {
    __shared__ int cnt[NBUK];
    int t = threadIdx.x;
    if (t < NBUK) cnt[t] = 0;
    __syncthreads();
    int base = blockIdx.x * CHUNK;
#pragma unroll
    for (int it = 0; it < 32; ++it) {
        int idx = it * 256 + t;
        if (idx < CHUNK) atomicAdd(&cnt[dst[base + idx] >> BSHIFT], 1);
    }
    __syncthreads();
    if (t < NBUK) C[blockIdx.x * NBUK + t] = cnt[t];
}

// ---------------- step 2: offsets. Off[c][b] = prefix over chunks; bbase = bucket bases -----
__global__ __launch_bounds__(256) void k_bscan(const int* __restrict__ C, int* __restrict__ Off,
                                               int* __restrict__ bbase) {
    __shared__ int s[256];
    int b = threadIdx.x;
    int tot = 0;
    if (b < NBUK) {
        for (int c = 0; c < NCHUNK; ++c) {
            Off[c * NBUK + b] = tot;
            tot += C[c * NBUK + b];
        }
    }
    s[b] = (b < NBUK) ? tot : 0;
    __syncthreads();
    for (int off = 1; off < 256; off <<= 1) {
        int v = (b >= off) ? s[b - off] : 0;
        __syncthreads();
        s[b] += v;
        __syncthreads();
    }
    if (b < NBUK) bbase[b] = s[b] - tot;   // exclusive
    if (b == 0) bbase[NBUK] = N_EDGES;
}

// ---------------- step 3: scatter packed records into bucket-grouped array ------------------
// record: (src:17)<<9 | (dst & 511)
__global__ __launch_bounds__(256) void k_scatter(const int* __restrict__ src, const int* __restrict__ dst,
                                                 const int* __restrict__ Off, const int* __restrict__ bbase,
                                                 unsigned* __restrict__ bkt) {
    __shared__ int cur[NBUK];
    int t = threadIdx.x;
    if (t < NBUK) cur[t] = bbase[t] + Off[blockIdx.x * NBUK + t];
    __syncthreads();
    int base = blockIdx.x * CHUNK;
#pragma unroll
    for (int it = 0; it < 32; ++it) {
        int idx = it * 256 + t;
        if (idx < CHUNK) {
            int s = src[base + idx], d = dst[base + idx];
            int b = d >> BSHIFT;
            int p = atomicAdd(&cur[b], 1);
            bkt[p] = ((unsigned)s << BSHIFT) | (unsigned)(d & (BSIZE - 1));
        }
    }
}

// ---------------- step 4: per-bucket degree hist -> deg, dinv, padded bucket total ----------
__global__ __launch_bounds__(256) void k_hist2(const unsigned* __restrict__ bkt,
                                               const int* __restrict__ bbase,
                                               int* __restrict__ deg, float* __restrict__ dinv,
                                               int* __restrict__ padTot) {
    __shared__ int hist[BSIZE];
    __shared__ int tot;
    int t = threadIdx.x, b = blockIdx.x;
    hist[t] = 0; hist[t + 256] = 0;
    if (t == 0) tot = 0;
    __syncthreads();
    int s0 = bbase[b], s1 = bbase[b + 1];
    for (int e = s0 + t; e < s1; e += 256) atomicAdd(&hist[bkt[e] & (BSIZE - 1)], 1);
    __syncthreads();
    int loc = 0;
#pragma unroll
    for (int h = 0; h < 2; ++h) {
        int l = t + h * 256;
        int node = b * BSIZE + l;
        int d = hist[l];
        if (node < N_NODES) {
            deg[node] = d;
            dinv[node] = rsqrtf((float)d + 1.0f);
        }
        loc += (d + 15) >> 4;
    }
    atomicAdd(&tot, loc);
    __syncthreads();
    if (t == 0) padTot[b] = tot << 4;
}

// ---------------- step 5: scan padded bucket totals -> padded bases ------------------------
__global__ __launch_bounds__(256) void k_pscan(const int* __restrict__ padTot, int* __restrict__ padBase,
                                               int* __restrict__ rowptrP) {
    __shared__ int s[256];
    int b = threadIdx.x;
    int v = (b < NBUK) ? padTot[b] : 0;
    s[b] = v;
    __syncthreads();
    for (int off = 1; off < 256; off <<= 1) {
        int u = (b >= off) ? s[b - off] : 0;
        __syncthreads();
        s[b] += u;
        __syncthreads();
    }
    if (b < NBUK) padBase[b] = s[b] - v;
    if (b == 0) {
        padBase[NBUK] = s[NBUK - 1];
        rowptrP[N_NODES] = s[NBUK - 1];
    }
}

// ---------------- step 6: per-bucket padded CSR + coef fused; dummy slots = record 0 --------
__global__ __launch_bounds__(256) void k_local2(const unsigned* __restrict__ bkt,
                                                const int* __restrict__ bbase,
                                                const int* __restrict__ deg,
                                                const float* __restrict__ dinv,
                                                const int* __restrict__ padBase,
                                                int* __restrict__ rowptrP,
                                                unsigned* __restrict__ edges) {
    __shared__ int sc[BSIZE];
    __shared__ int cur[BSIZE];
    __shared__ float dv[BSIZE];
    int t = threadIdx.x, b = blockIdx.x;
    int base = padBase[b];
    int n0 = b * BSIZE + t, n1 = n0 + 256;
    int d0 = (n0 < N_NODES) ? deg[n0] : 0;
    int d1 = (n1 < N_NODES) ? deg[n1] : 0;
    int p0 = ((d0 + 15) >> 4) << 4;
    int p1 = ((d1 + 15) >> 4) << 4;
    sc[t] = p0; sc[t + 256] = p1;
    dv[t] = (n0 < N_NODES) ? dinv[n0] : 0.f;
    dv[t + 256] = (n1 < N_NODES) ? dinv[n1] : 0.f;
    __syncthreads();
    for (int off = 1; off < BSIZE; off <<= 1) {
        int i0 = t, i1 = t + 256;
        int v0 = (i0 >= off) ? sc[i0 - off] : 0;
        int v1 = (i1 >= off) ? sc[i1 - off] : 0;
        __syncthreads();
        sc[i0] += v0; sc[i1] += v1;
        __syncthreads();
    }
    int off0 = base + sc[t] - p0;
    int off1 = base + sc[t + 256] - p1;
    if (n0 < N_NODES) rowptrP[n0] = off0;
    if (n1 < N_NODES) rowptrP[n1] = off1;
    cur[t] = off0; cur[t + 256] = off1;
    int padT = sc[BSIZE - 1];
    // init padded region to dummy (record 0 = src 0, coef 0)
    for (int i = base + t; i < base + padT; i += 256) edges[i] = 0;
    __syncthreads();
    int s0 = bbase[b], s1 = bbase[b + 1];
    for (int e = s0 + t; e < s1; e += 256) {
        unsigned r = bkt[e];
        int dl = (int)(r & (BSIZE - 1));
        int s = (int)(r >> BSHIFT);
        int p = atomicAdd(&cur[dl], 1);
        float c = dv[dl] * dinv[s];
        unsigned short cb = __builtin_bit_cast(unsigned short, (f16)c);
        edges[p] = ((unsigned)s << 15) | (unsigned)(cb & 0x7FFFu);
    }
}

// ---------------- FUSED layer 1: wave-parallel Agg(x) + (Nx4)@(4x128) GEMM, fp8 out ---------
// Block = 256 thr = 16 node-groups of 16 lanes. Edge lists padded to x16 -> no tail.
__global__ __launch_bounds__(256) void k_aggx1(const float4* __restrict__ x,
                                               const int* __restrict__ rowptrP,
                                               const unsigned* __restrict__ edges,
                                               const float* __restrict__ dinv,
                                               const float* __restrict__ W1, const float* __restrict__ b1,
                                               unsigned* __restrict__ hA) {
    __shared__ float4 sxa[16];
    __shared__ float sW[4 * HID];
    __shared__ float sb[HID];
    int t = threadIdx.x;
    sW[t] = W1[t];
    sW[t + 256] = W1[t + 256];
    if (t < HID) sb[t] = b1[t];
    int grp = t >> 4;             // 0..15 local node
    int l = t & 15;
    int node = blockIdx.x * 16 + grp;   // grid 6250 -> exact
    int beg = rowptrP[node], end = rowptrP[node + 1];
    float ax = 0.f, ay = 0.f, az = 0.f, aw = 0.f;
    for (int e = beg + l; e < end; e += 16) {
        unsigned r = edges[e];
        float c = rec_coef(r);
        float4 v = x[r >> 15];
        ax = fmaf(c, v.x, ax); ay = fmaf(c, v.y, ay);
        az = fmaf(c, v.z, az); aw = fmaf(c, v.w, aw);
    }
#pragma unroll
    for (int off = 1; off < 16; off <<= 1) {
        ax += __shfl_xor(ax, off, 64);
        ay += __shfl_xor(ay, off, 64);
        az += __shfl_xor(az, off, 64);
        aw += __shfl_xor(aw, off, 64);
    }
    if (l == 0) {
        float di = dinv[node];
        float c0 = di * di;
        float4 xv = x[node];
        sxa[grp] = make_float4(fmaf(c0, xv.x, ax), fmaf(c0, xv.y, ay),
                               fmaf(c0, xv.z, az), fmaf(c0, xv.w, aw));
    }
    __syncthreads();

    int node0 = blockIdx.x * 16;
#pragma unroll
    for (int it = 0; it < 2; ++it) {
        int id = it * 256 + t;       // 512 units = 16 nodes x 32 col-groups
        int n = id >> 5;
        int g = id & 31;
        float4 a = sxa[n];
        float c[4];
#pragma unroll
        for (int j = 0; j < 4; ++j) {
            int col = g * 4 + j;
            float v = sb[col];
            v = fmaf(a.x, sW[col],           v);
            v = fmaf(a.y, sW[HID + col],     v);
            v = fmaf(a.z, sW[2 * HID + col], v);
            v = fmaf(a.w, sW[3 * HID + col], v);
            c[j] = fmaxf(v, 0.0f);
        }
        unsigned lo = __hip_fp8x2_e4m3(make_float2(c[0], c[1])).__x;
        unsigned hi = __hip_fp8x2_e4m3(make_float2(c[2], c[3])).__x;
        hA[(node0 + n) * 32 + g] = lo | (hi << 16);
    }
}

// ---------------- FUSED layers 2..4: Agg (fp8, wave/node) -> LDS -> MFMA GEMM ---------------
// Block = 1024 thr = 16 waves = 16 nodes; each wave aggregates ITS node exactly like k_agg8p
// (full TLP preserved: 100000 waves). Result strip (16x128 f16) goes to swizzled LDS; after
// one barrier, waves 0..7 each compute one 16x16 column tile of the MFMA GEMM + bias + ReLU.
template <bool FP8OUT>
__global__ __launch_bounds__(1024, 8) void k_aggemm8(const unsigned* __restrict__ h8,
                                                     const int* __restrict__ rowptrP,
                                                     const unsigned* __restrict__ edges,
                                                     const float* __restrict__ dinv,
                                                     const f16* __restrict__ Wp,
                                                     const float* __restrict__ bias,
                                                     void* __restrict__ outv) {
    __shared__ f16 S[16 * HID];   // 4 KB, rows XOR-swizzled at dword granularity
    int wave = threadIdx.x >> 6;        // local node 0..15
    int lane = threadIdx.x & 63;
    int node0 = blockIdx.x * 16;
    int node = node0 + wave;
    int g = lane >> 4;
    int l = lane & 15;
    int beg = rowptrP[node], end = rowptrP[node + 1];
    const char* hp = (const char*)h8 + l * 8;

    float acc[8];
    {
        float di = dinv[node];
        float c0 = (g == 0) ? di * di : 0.0f;
        uint2 v = *(const uint2*)(hp + ((size_t)node << 7));
        float2 p0 = fp8x2_to_f32x2((unsigned short)(v.x & 0xFFFFu));
        float2 p1 = fp8x2_to_f32x2((unsigned short)(v.x >> 16));
        float2 p2 = fp8x2_to_f32x2((unsigned short)(v.y & 0xFFFFu));
        float2 p3 = fp8x2_to_f32x2((unsigned short)(v.y >> 16));
        acc[0] = c0 * p0.x; acc[1] = c0 * p0.y;
        acc[2] = c0 * p1.x; acc[3] = c0 * p1.y;
        acc[4] = c0 * p2.x; acc[5] = c0 * p2.y;
        acc[6] = c0 * p3.x; acc[7] = c0 * p3.y;
    }

    for (int e = beg; e < end; e += 16) {
        unsigned rec16 = edges[e + l];
#pragma unroll
        for (int i = 0; i < 4; ++i) {
            unsigned rec = __shfl(rec16, i * 4 + g, 64);
            float c = rec_coef(rec);
            uint2 v = *(const uint2*)(hp + ((rec >> 8) & 0xFFFFFF80u));
            fma8(c, v, acc);
        }
    }

#pragma unroll
    for (int j = 0; j < 8; ++j) {
        acc[j] += __shfl_xor(acc[j], 16, 64);
        acc[j] += __shfl_xor(acc[j], 32, 64);
    }
    if (lane < 16) {
        f16x8 o;
#pragma unroll
        for (int j = 0; j < 8; ++j) o[j] = (f16)acc[j];
        int dw = (l * 4) ^ ((wave & 7) << 2);       // dword offset within row, swizzled
        *(f16x8*)&S[wave * HID + dw * 2] = o;
    }
    __syncthreads();

    // GEMM phase: waves 0..7 each handle column tile t = wave
    if (wave < 8) {
        int t = wave;
        int m = lane & 15;
        int q = lane >> 4;
        f32x4 c4 = (f32x4){0.f, 0.f, 0.f, 0.f};
#pragma unroll
        for (int ks = 0; ks < 4; ++ks) {
            int dw = (ks * 16 + q * 4) ^ ((m & 7) << 2);
            f16x8 a = *(const f16x8*)&S[m * HID + dw * 2];
            f16x8 b = *(const f16x8*)(Wp + ((size_t)(t * 4 + ks) * 64 + lane) * 8);
            c4 = __builtin_amdgcn_mfma_f32_16x16x32_f16(a, b, c4, 0, 0, 0);
        }
        float bb = bias[t * 16 + m];
#pragma unroll
        for (int r = 0; r < 4; ++r) {
            float val = fmaxf(c4[r] + bb, 0.0f);
            int row = node0 + q * 4 + r;
            if constexpr (FP8OUT) {
                ((__hip_fp8_e4m3*)outv)[(size_t)row * HID + t * 16 + m] = __hip_fp8_e4m3(val);
            } else {
                ((f16*)outv)[(size_t)row * HID + t * 16 + m] = (f16)val;
            }
        }
    }
}

// ---------------- pack 3x W (128x128 fp32) into MFMA B-fragment order, fp16, one launch -----
__global__ __launch_bounds__(256) void k_packW3(const float* __restrict__ W2, const float* __restrict__ W3,
                                                const float* __restrict__ W4, f16* __restrict__ Wp) {
    int idx = blockIdx.x * 256 + threadIdx.x;   // 192 blocks x 256 = 49152 = 3 * 16384
    int which = idx >> 14;
    int r = idx & 16383;
    const float* W = (which == 0) ? W2 : (which == 1) ? W3 : W4;
    int j  = r & 7;
    int L  = (r >> 3) & 63;
    int ks = (r >> 9) & 3;
    int ct = r >> 11;
    int k = ks * 32 + (L >> 4) * 8 + j;
    int n = ct * 16 + (L & 15);
    Wp[idx] = (f16)W[k * HID + n];
}

// ---------------- pooling pass 1: per (graph, segment) partial sums, fp32, deterministic -----
__device__ __forceinline__ int lower_bound_batch(const int* __restrict__ batch, int val) {
    int lo = 0, hi = N_NODES;
    while (lo < hi) { int m = (lo + hi) >> 1; if (batch[m] < val) lo = m + 1; else hi = m; }
    return lo;
}

__global__ __launch_bounds__(128) void k_pool1(const f16* __restrict__ h, const int* __restrict__ batch,
                                               float* __restrict__ partials) {
    int g = blockIdx.x / POOL_SEG;
    int s = blockIdx.x % POOL_SEG;
    int f = threadIdx.x;
    int beg = lower_bound_batch(batch, g);
    int end = lower_bound_batch(batch, g + 1);
    int len = end - beg;
    int sb = beg + (int)(((long long)len * s) / POOL_SEG);
    int se = beg + (int)(((long long)len * (s + 1)) / POOL_SEG);
    float acc = 0.0f;
    for (int i = sb; i < se; ++i) acc += (float)h[i * HID + f];
    partials[(size_t)blockIdx.x * HID + f] = acc;
}

// ---------------- pooling pass 2 + head fused ---------------
__global__ __launch_bounds__(128) void k_pool2h(const float* __restrict__ partials,
                                                const int* __restrict__ batch,
                                                const float* __restrict__ Wl, const float* __restrict__ bl,
                                                float* __restrict__ out) {
    __shared__ float sp[HID];
    int g = blockIdx.x;
    int f = threadIdx.x;
    float acc = 0.0f;
#pragma unroll
    for (int s = 0; s < POOL_SEG; ++s)
        acc += partials[(size_t)(g * POOL_SEG + s) * HID + f];
    int beg = lower_bound_batch(batch, g);
    int end = lower_bound_batch(batch, g + 1);
    sp[f] = acc / fmaxf((float)(end - beg), 1.0f);
    __syncthreads();
    if (f < N_CLS) {
        float v = bl[f];
        for (int k = 0; k < HID; ++k) v = fmaf(sp[k], Wl[k * N_CLS + f], v);
        out[g * N_CLS + f] = 1.0f / (1.0f + expf(-v));
    }
}

extern "C" void kernel_launch(void* const* d_in, const int* in_sizes, int n_in,
                              void* d_out, int out_size, void* d_ws, size_t ws_size,
                              hipStream_t stream) {
    const float* x     = (const float*)d_in[0];
    const int*   ei    = (const int*)d_in[1];
    const int*   batch = (const int*)d_in[2];
    const float* W1 = (const float*)d_in[3];  const float* b1 = (const float*)d_in[4];
    const float* W2 = (const float*)d_in[5];  const float* b2 = (const float*)d_in[6];
    const float* W3 = (const float*)d_in[7];  const float* b3 = (const float*)d_in[8];
    const float* W4 = (const float*)d_in[9];  const float* b4 = (const float*)d_in[10];
    const float* Wl = (const float*)d_in[11]; const float* bl = (const float*)d_in[12];
    float* out = (float*)d_out;

    const size_t EPAD = (size_t)N_EDGES + (size_t)N_NODES * 16;   // padded edge capacity

    char* p = (char*)d_ws;
    auto alloc = [&](size_t bytes) { char* r = p; p += (bytes + 255) & ~(size_t)255; return (void*)r; };
    int*      C       = (int*)     alloc((size_t)NCHUNK * NBUK * 4);
    int*      Off     = (int*)     alloc((size_t)NCHUNK * NBUK * 4);
    int*      bbase   = (int*)     alloc((size_t)(NBUK + 1) * 4);
    int*      padTot  = (int*)     alloc((size_t)NBUK * 4);
    int*      padBase = (int*)     alloc((size_t)(NBUK + 1) * 4);
    unsigned* bkt     = (unsigned*)alloc((size_t)N_EDGES * 4);
    int*      deg     = (int*)     alloc((size_t)N_NODES * 4);
    int*      rowptrP = (int*)     alloc((size_t)(N_NODES + 1) * 4);
    float*    dinv    = (float*)   alloc((size_t)N_NODES * 4);
    unsigned* edges   = (unsigned*)alloc(EPAD * 4);
    unsigned* hA      = (unsigned*)alloc((size_t)N_NODES * HID);      // fp8 ping
    unsigned* hC      = (unsigned*)alloc((size_t)N_NODES * HID);      // fp8 pong
    f16*      h4      = (f16*)     alloc((size_t)N_NODES * HID * 2);  // fp16 final layer out
    float*    parts   = (float*)   alloc((size_t)N_GRAPH * POOL_SEG * HID * 4);
    f16*      Wp      = (f16*)     alloc((size_t)3 * HID * HID * 2);
    f16*      Wp2 = Wp;
    f16*      Wp3 = Wp + HID * HID;
    f16*      Wp4 = Wp + 2 * HID * HID;

    const int* srcv = ei;              // edge_index[0]
    const int* dstv = ei + N_EDGES;    // edge_index[1]

    // CSR build: bucketed, no global atomics, padded-to-16 rows, coef fused into scatter
    k_bc     <<<NCHUNK, 256, 0, stream>>>(dstv, C);
    k_bscan  <<<1, 256, 0, stream>>>(C, Off, bbase);
    k_scatter<<<NCHUNK, 256, 0, stream>>>(srcv, dstv, Off, bbase, bkt);
    k_hist2  <<<NBUK, 256, 0, stream>>>(bkt, bbase, deg, dinv, padTot);
    k_pscan  <<<1, 256, 0, stream>>>(padTot, padBase, rowptrP);
    k_local2 <<<NBUK, 256, 0, stream>>>(bkt, bbase, deg, dinv, padBase, rowptrP, edges);

    k_packW3<<<192, 256, 0, stream>>>(W2, W3, W4, Wp);

    // layer 1: fused wave-parallel Agg(x) + (Nx4)@(4x128) GEMM, fp8 out
    k_aggx1<<<N_NODES / 16, 256, 0, stream>>>((const float4*)x, rowptrP, edges, dinv, W1, b1, hA);

    // layers 2..4: fused Agg (fp8 gather, full TLP) + MFMA GEMM (+bias, ReLU)
    const int fgrid = N_NODES / 16;   // 6250, 1024-thread blocks
    k_aggemm8<true ><<<fgrid, 1024, 0, stream>>>(hA, rowptrP, edges, dinv, Wp2, b2, hC);
    k_aggemm8<true ><<<fgrid, 1024, 0, stream>>>(hC, rowptrP, edges, dinv, Wp3, b3, hA);
    k_aggemm8<false><<<fgrid, 1024, 0, stream>>>(hA, rowptrP, edges, dinv, Wp4, b4, h4);

    k_pool1 <<<N_GRAPH * POOL_SEG, 128, 0, stream>>>(h4, batch, parts);
    k_pool2h<<<N_GRAPH, 128, 0, stream>>>(parts, batch, Wl, bl, out);
}